// Round 13
// baseline (662.816 us; speedup 1.0000x reference)
//
#include <hip/hip_runtime.h>
#include <hip/hip_bf16.h>

#define CDIV(a,b) (((a)+(b)-1)/(b))

typedef __attribute__((ext_vector_type(8))) short bh8;     // 8 bf16 in 4 VGPRs
typedef __attribute__((ext_vector_type(4))) float f32x4;

__device__ __forceinline__ float gelu_exact(float x){
  return 0.5f * x * (1.0f + erff(x * 0.7071067811865475f));
}
__device__ __forceinline__ float blo(unsigned u){ return __uint_as_float(u << 16); }
__device__ __forceinline__ float bhi(unsigned u){ return __uint_as_float(u & 0xFFFF0000u); }

// ---------------- CSR build ----------------
__global__ void k_clear_int(int* __restrict__ p, int n){
  int i = blockIdx.x*256 + threadIdx.x;
  if (i < n) p[i] = 0;
}

__global__ void k_deg(const int* __restrict__ dst, int* __restrict__ deg, int E){
  int e = blockIdx.x*256 + threadIdx.x;
  if (e < E) atomicAdd(&deg[dst[e]], 1);
}

// ---- hierarchical scan: per-block exclusive scan + partials ----
__global__ void k_scan_blk(const int* __restrict__ deg, int* __restrict__ rowp,
                           int* __restrict__ partial, int N){
  __shared__ int buf[256];
  int i = blockIdx.x*256 + threadIdx.x;
  int v = (i < N) ? deg[i] : 0;
  buf[threadIdx.x] = v;
  __syncthreads();
  #pragma unroll
  for (int off = 1; off < 256; off <<= 1){
    int t = (threadIdx.x >= off) ? buf[threadIdx.x - off] : 0;
    __syncthreads();
    buf[threadIdx.x] += t;
    __syncthreads();
  }
  if (i < N) rowp[i] = buf[threadIdx.x] - v;        // exclusive within block
  if (threadIdx.x == 255) partial[blockIdx.x] = buf[255];
}

// single block: exclusive scan of partials (nb <= 256)
__global__ void k_scan_mid(int* __restrict__ partial, int nb){
  __shared__ int buf[256];
  int v = (threadIdx.x < nb) ? partial[threadIdx.x] : 0;
  buf[threadIdx.x] = v;
  __syncthreads();
  #pragma unroll
  for (int off = 1; off < 256; off <<= 1){
    int t = (threadIdx.x >= off) ? buf[threadIdx.x - off] : 0;
    __syncthreads();
    buf[threadIdx.x] += t;
    __syncthreads();
  }
  if (threadIdx.x < nb) partial[threadIdx.x] = buf[threadIdx.x] - v;  // exclusive
}

// adds block offsets; also emits cursor copy (replaces k_copy_int)
__global__ void k_scan_add(int* __restrict__ rowp, const int* __restrict__ partial,
                           int* __restrict__ cursor, int N, int E){
  int i = blockIdx.x*256 + threadIdx.x;
  if (i < N){
    int v = rowp[i] + partial[i >> 8];
    rowp[i] = v;
    cursor[i] = v;
  }
  if (i == 0) rowp[N] = E;
}

__global__ void k_fill(const int* __restrict__ src, const int* __restrict__ dst,
                       int* __restrict__ cursor, int* __restrict__ srcs, int E){
  int e = blockIdx.x*256 + threadIdx.x;
  if (e >= E) return;
  int d = dst[e];
  int pos = atomicAdd(&cursor[d], 1);
  srcs[pos] = src[e];
}

// ---- degree counting-sort: order[] = nodes sorted ascending by degree ----
__global__ void k_hist(const int* __restrict__ deg, int* __restrict__ hist, int N){
  int i = blockIdx.x*256 + threadIdx.x;
  if (i < N){
    int b = deg[i]; if (b > 1023) b = 1023;
    atomicAdd(&hist[b], 1);
  }
}

__global__ void k_scan_hist(int* __restrict__ hist){   // 1024 entries, single block
  __shared__ int buf[1024];
  int v = hist[threadIdx.x];
  buf[threadIdx.x] = v;
  __syncthreads();
  #pragma unroll
  for (int off = 1; off < 1024; off <<= 1){
    int t = (threadIdx.x >= off) ? buf[threadIdx.x - off] : 0;
    __syncthreads();
    buf[threadIdx.x] += t;
    __syncthreads();
  }
  hist[threadIdx.x] = buf[threadIdx.x] - v;   // exclusive
}

__global__ void k_place(const int* __restrict__ deg, int* __restrict__ hist,
                        int* __restrict__ order, int N){
  int i = blockIdx.x*256 + threadIdx.x;
  if (i < N){
    int b = deg[i]; if (b > 1023) b = 1023;
    int pos = atomicAdd(&hist[b], 1);
    order[pos] = i;
  }
}

// -------- fused weight prep: rel-fold + transpose + hi/lo split into MFMA frag order --------
// groups: 0=K (fused Ak), 1=Q, 2=V (fused Av), 3=O. Also computes beffK/beffV.
__global__ void k_prep(const float* __restrict__ Wk, const float* __restrict__ bk,
                       const float* __restrict__ Ak, const float* __restrict__ Wq,
                       const float* __restrict__ Wv, const float* __restrict__ bv,
                       const float* __restrict__ Av, const float* __restrict__ Wo,
                       short* __restrict__ BfH, short* __restrict__ BfL,
                       float* __restrict__ beffK, float* __restrict__ beffV){
  int t = blockIdx.x*256 + threadIdx.x;
  if (t < 4*16384){
    int g = t >> 14;
    int u = t & 16383;
    int k = u & 127, n = u >> 7;
    float x;
    if (g == 1)      x = Wq[(size_t)k*128 + n];
    else if (g == 3) x = Wo[(size_t)k*128 + n];
    else {
      const float* W = (g == 0) ? Wk : Wv;
      const float* A = (g == 0) ? Ak : Av;
      int h = n >> 5, e2 = n & 31;
      const float* s  = W + (size_t)k*128 + h*32;
      const float* Ah = A + h*1024 + e2;
      float acc = 0.f;
      #pragma unroll
      for (int d = 0; d < 32; ++d) acc += s[d] * Ah[d*32];
      x = acc;
    }
    unsigned ub = __float_as_uint(x);
    short hi = (short)(ub >> 16);
    float fh = __uint_as_float(ub & 0xFFFF0000u);
    short lo = (short)(__float_as_uint(x - fh) >> 16);
    int nt = n >> 4, lr = n & 15, ks = k >> 5, lk = (k >> 3) & 3, e = k & 7;
    size_t o = ((size_t)((g*8 + nt)*4 + ks)*64 + lr*4 + lk)*8 + e;
    BfH[o] = hi;
    BfL[o] = lo;
  } else {
    int u = t - 4*16384;       // 0..255: effective biases
    if (u < 256){
      int which = u >> 7, n = u & 127;
      const float* b = which ? bv : bk;
      const float* A = which ? Av : Ak;
      int h = n >> 5, e2 = n & 31;
      const float* Ah = A + h*1024 + e2;
      float acc = 0.f;
      #pragma unroll
      for (int d = 0; d < 32; ++d) acc += b[h*32 + d] * Ah[d*32];
      (which ? beffV : beffK)[n] = acc;
    }
  }
}

// ---------------- fused K/Q/V GEMM: reads fp32 A directly (frag-ordered loads + in-reg split) ----------------
// KV output: 8-short groups per node row: [K(4g..4g+3), V(4g..4g+3)] for g=c>>2;
// k_node lane L then reads one 16B uint4 = K-quad + V-quad.
__global__ __launch_bounds__(256)
void k_kqv(const float* __restrict__ A,
           const short* __restrict__ BfH, const short* __restrict__ BfL,
           const float* __restrict__ bK, const float* __restrict__ bQ,
           const float* __restrict__ bV,
           unsigned short* __restrict__ KV16, float* __restrict__ Qo, int M){
  const int tid = threadIdx.x;
  const int wm = tid >> 6, l = tid & 63;
  const int lr = l & 15, lk = l >> 4;
  const int perm = (lr*4 + lk)*8;
  const int p0 = blockIdx.x*8 + wm*2;

  bh8 a_h[2][4], a_l[2][4];
  #pragma unroll
  for (int p = 0; p < 2; ++p){
    int row = (p0 + p)*16 + lr;
    #pragma unroll
    for (int ks = 0; ks < 4; ++ks){
      float f[8] = {0.f,0.f,0.f,0.f,0.f,0.f,0.f,0.f};
      if (row < M){
        float4 va = *(const float4*)(A + (size_t)row*128 + ks*32 + lk*8);
        float4 vb = *(const float4*)(A + (size_t)row*128 + ks*32 + lk*8 + 4);
        f[0]=va.x; f[1]=va.y; f[2]=va.z; f[3]=va.w;
        f[4]=vb.x; f[5]=vb.y; f[6]=vb.z; f[7]=vb.w;
      }
      bh8 h8, l8;
      #pragma unroll
      for (int q = 0; q < 8; ++q){
        unsigned ub = __float_as_uint(f[q]);
        h8[q] = (short)(ub >> 16);
        float fhv = __uint_as_float(ub & 0xFFFF0000u);
        l8[q] = (short)(__float_as_uint(f[q] - fhv) >> 16);
      }
      a_h[p][ks] = h8;
      a_l[p][ks] = l8;
    }
  }

  #pragma unroll
  for (int g = 0; g < 3; ++g){
    f32x4 acc[2][8];
    #pragma unroll
    for (int p = 0; p < 2; ++p)
      #pragma unroll
      for (int i = 0; i < 8; ++i) acc[p][i] = (f32x4){0.f,0.f,0.f,0.f};
    #pragma unroll
    for (int ks = 0; ks < 4; ++ks){
      #pragma unroll
      for (int nt = 0; nt < 8; ++nt){
        size_t o = (size_t)((g*8 + nt)*4 + ks)*512 + perm;
        bh8 bh_ = *(const bh8*)(BfH + o);
        bh8 bl_ = *(const bh8*)(BfL + o);
        #pragma unroll
        for (int p = 0; p < 2; ++p){
          acc[p][nt] = __builtin_amdgcn_mfma_f32_16x16x32_bf16(a_h[p][ks], bh_, acc[p][nt], 0, 0, 0);
          acc[p][nt] = __builtin_amdgcn_mfma_f32_16x16x32_bf16(a_l[p][ks], bh_, acc[p][nt], 0, 0, 0);
          acc[p][nt] = __builtin_amdgcn_mfma_f32_16x16x32_bf16(a_h[p][ks], bl_, acc[p][nt], 0, 0, 0);
        }
      }
    }
    const float* bias = (g==0) ? bK : (g==1) ? bQ : bV;
    #pragma unroll
    for (int p = 0; p < 2; ++p){
      int r0 = (p0 + p)*16 + lk*4;
      #pragma unroll
      for (int nt = 0; nt < 8; ++nt){
        int c = nt*16 + lr;
        float bs = bias[c];
        #pragma unroll
        for (int i = 0; i < 4; ++i){
          int r = r0 + i;
          if (r >= M) continue;
          float o = acc[p][nt][i] + bs;
          if (g == 1){
            Qo[(size_t)r*128 + c] = o;
          } else {
            __hip_bfloat16 b16 = __float2bfloat16(o);
            size_t idx = (size_t)r*256 + (size_t)(c >> 2)*8 + ((g == 2) ? 4 : 0) + (c & 3);
            KV16[idx] = *(unsigned short*)&b16;
          }
        }
      }
    }
  }
}

// ---------------- out GEMM: h = sg*(gelu(agg)@Wo + bo) + (1-sg)*hin ----------------
__global__ __launch_bounds__(256)
void k_outgemm(const short* __restrict__ AfH, const short* __restrict__ AfL,
               const short* __restrict__ BfH, const short* __restrict__ BfL,
               const float* __restrict__ bias, const float* __restrict__ mixsrc,
               const float* __restrict__ skipp, float* __restrict__ out, int M){
  const int tid = threadIdx.x;
  const int wm = tid >> 6, l = tid & 63;
  const int lr = l & 15, lk = l >> 4;
  const int perm = (lr*4 + lk)*8;
  const int p0 = blockIdx.x*8 + wm*2;

  bh8 a_h[2][4], a_l[2][4];
  #pragma unroll
  for (int p = 0; p < 2; ++p)
    #pragma unroll
    for (int ks = 0; ks < 4; ++ks){
      size_t o = (size_t)((p0 + p)*4 + ks)*512 + perm;
      a_h[p][ks] = *(const bh8*)(AfH + o);
      a_l[p][ks] = *(const bh8*)(AfL + o);
    }

  f32x4 acc[2][8];
  #pragma unroll
  for (int p = 0; p < 2; ++p)
    #pragma unroll
    for (int i = 0; i < 8; ++i) acc[p][i] = (f32x4){0.f,0.f,0.f,0.f};
  #pragma unroll
  for (int ks = 0; ks < 4; ++ks){
    #pragma unroll
    for (int nt = 0; nt < 8; ++nt){
      size_t o = (size_t)((3*8 + nt)*4 + ks)*512 + perm;
      bh8 bh_ = *(const bh8*)(BfH + o);
      bh8 bl_ = *(const bh8*)(BfL + o);
      #pragma unroll
      for (int p = 0; p < 2; ++p){
        acc[p][nt] = __builtin_amdgcn_mfma_f32_16x16x32_bf16(a_h[p][ks], bh_, acc[p][nt], 0, 0, 0);
        acc[p][nt] = __builtin_amdgcn_mfma_f32_16x16x32_bf16(a_l[p][ks], bh_, acc[p][nt], 0, 0, 0);
        acc[p][nt] = __builtin_amdgcn_mfma_f32_16x16x32_bf16(a_h[p][ks], bl_, acc[p][nt], 0, 0, 0);
      }
    }
  }
  float sg = 1.f / (1.f + expf(-skipp[0]));
  #pragma unroll
  for (int p = 0; p < 2; ++p){
    int r0 = (p0 + p)*16 + lk*4;
    #pragma unroll
    for (int nt = 0; nt < 8; ++nt){
      int c = nt*16 + lr;
      float bs = bias[c];
      #pragma unroll
      for (int i = 0; i < 4; ++i){
        int r = r0 + i;
        if (r >= M) continue;
        float o = acc[p][nt][i] + bs;
        o = sg*o + (1.f - sg)*mixsrc[(size_t)r*128 + c];
        out[(size_t)r*128 + c] = o;
      }
    }
  }
}

// ---------------- fused attention: 2 degree-paired nodes per wave, unroll-4 ----------------
// Half-wave owns one node (via degree-sorted order[]); L=lane&31 owns channels 4L..4L+3;
// head h=L>>3 (8-lane groups, 3-shfl reduce). One 16B gather per edge per lane.
__global__ __launch_bounds__(256)
void k_node(const unsigned short* __restrict__ KV, const float* __restrict__ Qb,
            const int* __restrict__ srcs, const int* __restrict__ row_ptr,
            const int* __restrict__ order, const float* __restrict__ p,
            short* __restrict__ fh, short* __restrict__ fl, int NN){
  int wave = threadIdx.x >> 6;
  int lane = threadIdx.x & 63;
  int L = lane & 31;
  int gid = blockIdx.x*8 + wave*2 + (lane >> 5);
  if (gid >= NN) return;
  int node = order[gid];
  int start = row_ptr[node], end = row_ptr[node+1];
  int h = L >> 3;
  float ph = p[h] * 0.25504366769049834f;    // (1/sqrt(32))*log2(e)*p[h]
  const unsigned short* KVl = KV + L*8;
  float4 qv = *(const float4*)(Qb + (size_t)node*128 + L*4);

  float a0=0.f, a1=0.f, a2=0.f, a3=0.f, den=0.f;
  int j = start;
  for (; j + 3 < end; j += 4){
    int s0 = srcs[j], s1 = srcs[j+1], s2 = srcs[j+2], s3 = srcs[j+3];
    uint4 kv0 = *(const uint4*)(KVl + (size_t)s0*256);
    uint4 kv1 = *(const uint4*)(KVl + (size_t)s1*256);
    uint4 kv2 = *(const uint4*)(KVl + (size_t)s2*256);
    uint4 kv3 = *(const uint4*)(KVl + (size_t)s3*256);
    float d0 = blo(kv0.x)*qv.x + bhi(kv0.x)*qv.y + blo(kv0.y)*qv.z + bhi(kv0.y)*qv.w;
    float d1 = blo(kv1.x)*qv.x + bhi(kv1.x)*qv.y + blo(kv1.y)*qv.z + bhi(kv1.y)*qv.w;
    float d2 = blo(kv2.x)*qv.x + bhi(kv2.x)*qv.y + blo(kv2.y)*qv.z + bhi(kv2.y)*qv.w;
    float d3 = blo(kv3.x)*qv.x + bhi(kv3.x)*qv.y + blo(kv3.y)*qv.z + bhi(kv3.y)*qv.w;
    #pragma unroll
    for (int m = 1; m < 8; m <<= 1){
      d0 += __shfl_xor(d0, m);
      d1 += __shfl_xor(d1, m);
      d2 += __shfl_xor(d2, m);
      d3 += __shfl_xor(d3, m);
    }
    float w0 = exp2f(d0 * ph);
    float w1 = exp2f(d1 * ph);
    float w2 = exp2f(d2 * ph);
    float w3 = exp2f(d3 * ph);
    den += (w0 + w1) + (w2 + w3);
    a0 += (w0*blo(kv0.z) + w1*blo(kv1.z)) + (w2*blo(kv2.z) + w3*blo(kv3.z));
    a1 += (w0*bhi(kv0.z) + w1*bhi(kv1.z)) + (w2*bhi(kv2.z) + w3*bhi(kv3.z));
    a2 += (w0*blo(kv0.w) + w1*blo(kv1.w)) + (w2*blo(kv2.w) + w3*blo(kv3.w));
    a3 += (w0*bhi(kv0.w) + w1*bhi(kv1.w)) + (w2*bhi(kv2.w) + w3*bhi(kv3.w));
  }
  for (; j < end; ++j){
    int s0 = srcs[j];
    uint4 kv0 = *(const uint4*)(KVl + (size_t)s0*256);
    float d0 = blo(kv0.x)*qv.x + bhi(kv0.x)*qv.y + blo(kv0.y)*qv.z + bhi(kv0.y)*qv.w;
    #pragma unroll
    for (int m = 1; m < 8; m <<= 1) d0 += __shfl_xor(d0, m);
    float w0 = exp2f(d0 * ph);
    den += w0;
    a0 += w0*blo(kv0.z);
    a1 += w0*bhi(kv0.z);
    a2 += w0*blo(kv0.w);
    a3 += w0*bhi(kv0.w);
  }
  float o[4] = {0.f, 0.f, 0.f, 0.f};
  if (end > start){
    float inv = 1.f / den;
    o[0] = gelu_exact(a0 * inv);
    o[1] = gelu_exact(a1 * inv);
    o[2] = gelu_exact(a2 * inv);
    o[3] = gelu_exact(a3 * inv);
  }
  // split hi/lo; 4 adjacent k-slots -> one 8B store per buffer (frag map = prep map)
  unsigned hh[4], ll[4];
  #pragma unroll
  for (int q = 0; q < 4; ++q){
    unsigned ub = __float_as_uint(o[q]);
    hh[q] = ub >> 16;
    ll[q] = __float_as_uint(o[q] - __uint_as_float(ub & 0xFFFF0000u)) >> 16;
  }
  size_t ci = (size_t)((node >> 4)*4 + h)*64 + (node & 15)*4 + ((L >> 1) & 3);
  size_t si = ci*8 + (L & 1)*4;
  uint2 uh = make_uint2(hh[0] | (hh[1] << 16), hh[2] | (hh[3] << 16));
  uint2 ul = make_uint2(ll[0] | (ll[1] << 16), ll[2] | (ll[3] << 16));
  *(uint2*)(fh + si) = uh;
  *(uint2*)(fl + si) = ul;
}

// ---------------- decoder ----------------
__global__ void k_gemv2(const float* __restrict__ z, const float* __restrict__ Wlp,
                        float* __restrict__ s1, float* __restrict__ s2, int NN){
  int n = blockIdx.x*256 + threadIdx.x;
  if (n >= NN) return;
  const float4* row = (const float4*)(z + (size_t)n*128);
  float a0 = 0.f, a1 = 0.f;
  #pragma unroll
  for (int i = 0; i < 32; ++i){
    float4 v  = row[i];
    float4 w1 = ((const float4*)Wlp)[i];
    float4 w2 = ((const float4*)Wlp)[32 + i];
    a0 += v.x*w1.x + v.y*w1.y + v.z*w1.z + v.w*w1.w;
    a1 += v.x*w2.x + v.y*w2.y + v.z*w2.z + v.w*w2.w;
  }
  s1[n] = a0; s2[n] = a1;
}

__global__ void k_decode(const int* __restrict__ pe, const int* __restrict__ ne,
                         const float* __restrict__ s1, const float* __restrict__ s2,
                         const float* __restrict__ blp, float* __restrict__ out, int P){
  int i = blockIdx.x*256 + threadIdx.x;
  if (i < P){
    out[i] = s1[pe[i]] + s2[pe[P + i]] + blp[0];
  } else if (i < 2*P){
    int j = i - P;
    out[P + j] = s1[ne[j]] + s2[ne[P + j]] + blp[0];
  }
}

extern "C" void kernel_launch(void* const* d_in, const int* in_sizes, int n_in,
                              void* d_out, int out_size, void* d_ws, size_t ws_size,
                              hipStream_t stream){
  const float* x      = (const float*)d_in[0];
  const int*   ei     = (const int*)d_in[1];
  const int*   pos_ei = (const int*)d_in[3];
  const int*   neg_ei = (const int*)d_in[4];
  const int NN = in_sizes[0] / 128;
  const int E  = in_sizes[1] / 2;
  const int P  = in_sizes[3] / 2;
  const int padM = CDIV(NN, 128) * 128;
  const int* e_src = ei;
  const int* e_dst = ei + E;

  char* wsb = (char*)d_ws;
  size_t off = 0;
  auto alloc = [&](size_t bytes)->char*{
    char* r = wsb + off;
    off = (off + bytes + 255) & ~(size_t)255;
    return r;
  };
  unsigned short* KV16 = (unsigned short*)alloc((size_t)NN*256*2);  // interleaved K/V quads
  float* Qb     = (float*)alloc((size_t)NN*128*4);
  float* h1     = (float*)alloc((size_t)NN*128*4);
  short* AfH    = (short*)alloc((size_t)padM*128*2);   // gelu(agg) frags from k_node
  short* AfL    = (short*)alloc((size_t)padM*128*2);
  int*   srcs   = (int*)alloc((size_t)E*4);
  int*   rowp   = (int*)alloc((size_t)(NN+1)*4);
  int*   deg    = (int*)alloc((size_t)NN*4);
  int*   cursor = (int*)alloc((size_t)NN*4);
  int*   order  = (int*)alloc((size_t)NN*4);
  int*   hist   = (int*)alloc(1024*4);
  int*   partial= (int*)alloc(256*4);
  float* beffK  = (float*)alloc(128*4);
  float* beffV  = (float*)alloc(128*4);
  short* BfH    = (short*)alloc((size_t)4*16384*2);
  short* BfL    = (short*)alloc((size_t)4*16384*2);
  float* s1     = (float*)alloc((size_t)NN*4);
  float* s2     = (float*)alloc((size_t)NN*4);
  float* h2     = Qb;   // Qb dead after layer-2 k_node; layer-2 outgemm then writes it

  // ---- CSR + degree sort (shared by both layers) ----
  const int nb = CDIV(NN, 256);     // 196 <= 256
  k_clear_int<<<CDIV(NN,256),256,0,stream>>>(deg, NN);
  k_clear_int<<<4,256,0,stream>>>(hist, 1024);
  k_deg<<<CDIV(E,256),256,0,stream>>>(e_dst, deg, E);
  k_scan_blk<<<nb,256,0,stream>>>(deg, rowp, partial, NN);
  k_scan_mid<<<1,256,0,stream>>>(partial, nb);
  k_scan_add<<<CDIV(NN,256),256,0,stream>>>(rowp, partial, cursor, NN, E);
  k_fill<<<CDIV(E,256),256,0,stream>>>(e_src, e_dst, cursor, srcs, E);
  k_hist<<<CDIV(NN,256),256,0,stream>>>(deg, hist, NN);
  k_scan_hist<<<1,1024,0,stream>>>(hist);
  k_place<<<CDIV(NN,256),256,0,stream>>>(deg, hist, order, NN);

  const int gblk = padM / 128;
  auto layer = [&](const float* hin, float* hout, int base){
    const float* Wk  = (const float*)d_in[base+0];
    const float* bk  = (const float*)d_in[base+1];
    const float* Wq  = (const float*)d_in[base+2];
    const float* bq  = (const float*)d_in[base+3];
    const float* Wv  = (const float*)d_in[base+4];
    const float* bv  = (const float*)d_in[base+5];
    const float* a   = (const float*)d_in[base+6];
    const float* m   = (const float*)d_in[base+7];
    const float* p   = (const float*)d_in[base+8];
    const float* Wo  = (const float*)d_in[base+9];
    const float* bo  = (const float*)d_in[base+10];
    const float* sk  = (const float*)d_in[base+11];
    k_prep<<<CDIV(4*16384+256,256),256,0,stream>>>(Wk, bk, a, Wq, Wv, bv, m, Wo,
                                                   BfH, BfL, beffK, beffV);
    k_kqv<<<gblk,256,0,stream>>>(hin, BfH, BfL, beffK, bq, beffV, KV16, Qb, NN);
    k_node<<<CDIV(NN,8),256,0,stream>>>(KV16, Qb, srcs, rowp, order, p, AfH, AfL, NN);
    k_outgemm<<<gblk,256,0,stream>>>(AfH, AfL, BfH, BfL, bo, hin, sk, hout, NN);
  };
  layer(x,  h1, 5);
  layer(h1, h2, 17);

  k_gemv2<<<CDIV(NN,256),256,0,stream>>>(h2, (const float*)d_in[29], s1, s2, NN);
  k_decode<<<CDIV(2*P,256),256,0,stream>>>(pos_ei, neg_ei, s1, s2,
                                           (const float*)d_in[30], (float*)d_out, P);
}

// Round 14
// 386.291 us; speedup vs baseline: 1.7158x; 1.7158x over previous
//
#include <hip/hip_runtime.h>
#include <hip/hip_bf16.h>

#define CDIV(a,b) (((a)+(b)-1)/(b))

typedef __attribute__((ext_vector_type(8))) short bh8;     // 8 bf16 in 4 VGPRs
typedef __attribute__((ext_vector_type(4))) float f32x4;

__device__ __forceinline__ float gelu_exact(float x){
  return 0.5f * x * (1.0f + erff(x * 0.7071067811865475f));
}
__device__ __forceinline__ float blo(unsigned u){ return __uint_as_float(u << 16); }
__device__ __forceinline__ float bhi(unsigned u){ return __uint_as_float(u & 0xFFFF0000u); }

// ---------------- CSR build ----------------
__global__ void k_clear_int(int* __restrict__ p, int n){
  int i = blockIdx.x*256 + threadIdx.x;
  if (i < n) p[i] = 0;
}

__global__ void k_deg(const int* __restrict__ dst, int* __restrict__ deg, int E){
  int e = blockIdx.x*256 + threadIdx.x;
  if (e < E) atomicAdd(&deg[dst[e]], 1);
}

// ---- hierarchical scan: per-block exclusive scan + partials ----
__global__ void k_scan_blk(const int* __restrict__ deg, int* __restrict__ rowp,
                           int* __restrict__ partial, int N){
  __shared__ int buf[256];
  int i = blockIdx.x*256 + threadIdx.x;
  int v = (i < N) ? deg[i] : 0;
  buf[threadIdx.x] = v;
  __syncthreads();
  #pragma unroll
  for (int off = 1; off < 256; off <<= 1){
    int t = (threadIdx.x >= off) ? buf[threadIdx.x - off] : 0;
    __syncthreads();
    buf[threadIdx.x] += t;
    __syncthreads();
  }
  if (i < N) rowp[i] = buf[threadIdx.x] - v;        // exclusive within block
  if (threadIdx.x == 255) partial[blockIdx.x] = buf[255];
}

// single block: exclusive scan of partials (nb <= 256)
__global__ void k_scan_mid(int* __restrict__ partial, int nb){
  __shared__ int buf[256];
  int v = (threadIdx.x < nb) ? partial[threadIdx.x] : 0;
  buf[threadIdx.x] = v;
  __syncthreads();
  #pragma unroll
  for (int off = 1; off < 256; off <<= 1){
    int t = (threadIdx.x >= off) ? buf[threadIdx.x - off] : 0;
    __syncthreads();
    buf[threadIdx.x] += t;
    __syncthreads();
  }
  if (threadIdx.x < nb) partial[threadIdx.x] = buf[threadIdx.x] - v;  // exclusive
}

// adds block offsets; also emits cursor copy
__global__ void k_scan_add(int* __restrict__ rowp, const int* __restrict__ partial,
                           int* __restrict__ cursor, int N, int E){
  int i = blockIdx.x*256 + threadIdx.x;
  if (i < N){
    int v = rowp[i] + partial[i >> 8];
    rowp[i] = v;
    cursor[i] = v;
  }
  if (i == 0) rowp[N] = E;
}

__global__ void k_fill(const int* __restrict__ src, const int* __restrict__ dst,
                       int* __restrict__ cursor, int* __restrict__ srcs, int E){
  int e = blockIdx.x*256 + threadIdx.x;
  if (e >= E) return;
  int d = dst[e];
  int pos = atomicAdd(&cursor[d], 1);
  srcs[pos] = src[e];
}

// -------- fused weight prep: rel-fold + transpose + hi/lo split into MFMA frag order --------
// groups: 0=K (fused Ak), 1=Q, 2=V (fused Av), 3=O. Also computes beffK/beffV.
__global__ void k_prep(const float* __restrict__ Wk, const float* __restrict__ bk,
                       const float* __restrict__ Ak, const float* __restrict__ Wq,
                       const float* __restrict__ Wv, const float* __restrict__ bv,
                       const float* __restrict__ Av, const float* __restrict__ Wo,
                       short* __restrict__ BfH, short* __restrict__ BfL,
                       float* __restrict__ beffK, float* __restrict__ beffV){
  int t = blockIdx.x*256 + threadIdx.x;
  if (t < 4*16384){
    int g = t >> 14;
    int u = t & 16383;
    int k = u & 127, n = u >> 7;
    float x;
    if (g == 1)      x = Wq[(size_t)k*128 + n];
    else if (g == 3) x = Wo[(size_t)k*128 + n];
    else {
      const float* W = (g == 0) ? Wk : Wv;
      const float* A = (g == 0) ? Ak : Av;
      int h = n >> 5, e2 = n & 31;
      const float* s  = W + (size_t)k*128 + h*32;
      const float* Ah = A + h*1024 + e2;
      float acc = 0.f;
      #pragma unroll
      for (int d = 0; d < 32; ++d) acc += s[d] * Ah[d*32];
      x = acc;
    }
    unsigned ub = __float_as_uint(x);
    short hi = (short)(ub >> 16);
    float fh = __uint_as_float(ub & 0xFFFF0000u);
    short lo = (short)(__float_as_uint(x - fh) >> 16);
    int nt = n >> 4, lr = n & 15, ks = k >> 5, lk = (k >> 3) & 3, e = k & 7;
    size_t o = ((size_t)((g*8 + nt)*4 + ks)*64 + lr*4 + lk)*8 + e;
    BfH[o] = hi;
    BfL[o] = lo;
  } else {
    int u = t - 4*16384;       // 0..255: effective biases
    if (u < 256){
      int which = u >> 7, n = u & 127;
      const float* b = which ? bv : bk;
      const float* A = which ? Av : Ak;
      int h = n >> 5, e2 = n & 31;
      const float* Ah = A + h*1024 + e2;
      float acc = 0.f;
      #pragma unroll
      for (int d = 0; d < 32; ++d) acc += b[h*32 + d] * Ah[d*32];
      (which ? beffV : beffK)[n] = acc;
    }
  }
}

// ---------------- fused K/Q/V GEMM: reads fp32 A directly (frag-ordered loads + in-reg split) ----------------
// KV output: 8-short groups per node row: [K(4g..4g+3), V(4g..4g+3)] for g=c>>2;
// k_node lane L then reads one 16B uint4 = K-quad + V-quad.
__global__ __launch_bounds__(256)
void k_kqv(const float* __restrict__ A,
           const short* __restrict__ BfH, const short* __restrict__ BfL,
           const float* __restrict__ bK, const float* __restrict__ bQ,
           const float* __restrict__ bV,
           unsigned short* __restrict__ KV16, float* __restrict__ Qo, int M){
  const int tid = threadIdx.x;
  const int wm = tid >> 6, l = tid & 63;
  const int lr = l & 15, lk = l >> 4;
  const int perm = (lr*4 + lk)*8;
  const int p0 = blockIdx.x*8 + wm*2;

  bh8 a_h[2][4], a_l[2][4];
  #pragma unroll
  for (int p = 0; p < 2; ++p){
    int row = (p0 + p)*16 + lr;
    #pragma unroll
    for (int ks = 0; ks < 4; ++ks){
      float f[8] = {0.f,0.f,0.f,0.f,0.f,0.f,0.f,0.f};
      if (row < M){
        float4 va = *(const float4*)(A + (size_t)row*128 + ks*32 + lk*8);
        float4 vb = *(const float4*)(A + (size_t)row*128 + ks*32 + lk*8 + 4);
        f[0]=va.x; f[1]=va.y; f[2]=va.z; f[3]=va.w;
        f[4]=vb.x; f[5]=vb.y; f[6]=vb.z; f[7]=vb.w;
      }
      bh8 h8, l8;
      #pragma unroll
      for (int q = 0; q < 8; ++q){
        unsigned ub = __float_as_uint(f[q]);
        h8[q] = (short)(ub >> 16);
        float fhv = __uint_as_float(ub & 0xFFFF0000u);
        l8[q] = (short)(__float_as_uint(f[q] - fhv) >> 16);
      }
      a_h[p][ks] = h8;
      a_l[p][ks] = l8;
    }
  }

  #pragma unroll
  for (int g = 0; g < 3; ++g){
    f32x4 acc[2][8];
    #pragma unroll
    for (int p = 0; p < 2; ++p)
      #pragma unroll
      for (int i = 0; i < 8; ++i) acc[p][i] = (f32x4){0.f,0.f,0.f,0.f};
    #pragma unroll
    for (int ks = 0; ks < 4; ++ks){
      #pragma unroll
      for (int nt = 0; nt < 8; ++nt){
        size_t o = (size_t)((g*8 + nt)*4 + ks)*512 + perm;
        bh8 bh_ = *(const bh8*)(BfH + o);
        bh8 bl_ = *(const bh8*)(BfL + o);
        #pragma unroll
        for (int p = 0; p < 2; ++p){
          acc[p][nt] = __builtin_amdgcn_mfma_f32_16x16x32_bf16(a_h[p][ks], bh_, acc[p][nt], 0, 0, 0);
          acc[p][nt] = __builtin_amdgcn_mfma_f32_16x16x32_bf16(a_l[p][ks], bh_, acc[p][nt], 0, 0, 0);
          acc[p][nt] = __builtin_amdgcn_mfma_f32_16x16x32_bf16(a_h[p][ks], bl_, acc[p][nt], 0, 0, 0);
        }
      }
    }
    const float* bias = (g==0) ? bK : (g==1) ? bQ : bV;
    #pragma unroll
    for (int p = 0; p < 2; ++p){
      int r0 = (p0 + p)*16 + lk*4;
      #pragma unroll
      for (int nt = 0; nt < 8; ++nt){
        int c = nt*16 + lr;
        float bs = bias[c];
        #pragma unroll
        for (int i = 0; i < 4; ++i){
          int r = r0 + i;
          if (r >= M) continue;
          float o = acc[p][nt][i] + bs;
          if (g == 1){
            Qo[(size_t)r*128 + c] = o;
          } else {
            __hip_bfloat16 b16 = __float2bfloat16(o);
            size_t idx = (size_t)r*256 + (size_t)(c >> 2)*8 + ((g == 2) ? 4 : 0) + (c & 3);
            KV16[idx] = *(unsigned short*)&b16;
          }
        }
      }
    }
  }
}

// ---------------- out GEMM: h = sg*(gelu(agg)@Wo + bo) + (1-sg)*hin ----------------
__global__ __launch_bounds__(256)
void k_outgemm(const short* __restrict__ AfH, const short* __restrict__ AfL,
               const short* __restrict__ BfH, const short* __restrict__ BfL,
               const float* __restrict__ bias, const float* __restrict__ mixsrc,
               const float* __restrict__ skipp, float* __restrict__ out, int M){
  const int tid = threadIdx.x;
  const int wm = tid >> 6, l = tid & 63;
  const int lr = l & 15, lk = l >> 4;
  const int perm = (lr*4 + lk)*8;
  const int p0 = blockIdx.x*8 + wm*2;

  bh8 a_h[2][4], a_l[2][4];
  #pragma unroll
  for (int p = 0; p < 2; ++p)
    #pragma unroll
    for (int ks = 0; ks < 4; ++ks){
      size_t o = (size_t)((p0 + p)*4 + ks)*512 + perm;
      a_h[p][ks] = *(const bh8*)(AfH + o);
      a_l[p][ks] = *(const bh8*)(AfL + o);
    }

  f32x4 acc[2][8];
  #pragma unroll
  for (int p = 0; p < 2; ++p)
    #pragma unroll
    for (int i = 0; i < 8; ++i) acc[p][i] = (f32x4){0.f,0.f,0.f,0.f};
  #pragma unroll
  for (int ks = 0; ks < 4; ++ks){
    #pragma unroll
    for (int nt = 0; nt < 8; ++nt){
      size_t o = (size_t)((3*8 + nt)*4 + ks)*512 + perm;
      bh8 bh_ = *(const bh8*)(BfH + o);
      bh8 bl_ = *(const bh8*)(BfL + o);
      #pragma unroll
      for (int p = 0; p < 2; ++p){
        acc[p][nt] = __builtin_amdgcn_mfma_f32_16x16x32_bf16(a_h[p][ks], bh_, acc[p][nt], 0, 0, 0);
        acc[p][nt] = __builtin_amdgcn_mfma_f32_16x16x32_bf16(a_l[p][ks], bh_, acc[p][nt], 0, 0, 0);
        acc[p][nt] = __builtin_amdgcn_mfma_f32_16x16x32_bf16(a_h[p][ks], bl_, acc[p][nt], 0, 0, 0);
      }
    }
  }
  float sg = 1.f / (1.f + expf(-skipp[0]));
  #pragma unroll
  for (int p = 0; p < 2; ++p){
    int r0 = (p0 + p)*16 + lk*4;
    #pragma unroll
    for (int nt = 0; nt < 8; ++nt){
      int c = nt*16 + lr;
      float bs = bias[c];
      #pragma unroll
      for (int i = 0; i < 4; ++i){
        int r = r0 + i;
        if (r >= M) continue;
        float o = acc[p][nt][i] + bs;
        o = sg*o + (1.f - sg)*mixsrc[(size_t)r*128 + c];
        out[(size_t)r*128 + c] = o;
      }
    }
  }
}

// ---------------- fused attention: 2 nodes per wave, unroll-4 (8 edges in flight/wave) ----------------
// Half-wave owns one node; L=lane&31 owns channels 4L..4L+3; head h=L>>3 (8-lane groups,
// 3-shfl reduce). One 16B gather per edge per lane (K-quad + V-quad). No max-shift.
__global__ __launch_bounds__(256)
void k_node(const unsigned short* __restrict__ KV, const float* __restrict__ Qb,
            const int* __restrict__ srcs, const int* __restrict__ row_ptr,
            const float* __restrict__ p,
            short* __restrict__ fh, short* __restrict__ fl, int NN){
  int wave = threadIdx.x >> 6;
  int lane = threadIdx.x & 63;
  int L = lane & 31;
  int node = blockIdx.x*8 + wave*2 + (lane >> 5);
  if (node >= NN) return;
  int start = row_ptr[node], end = row_ptr[node+1];
  int h = L >> 3;
  float ph = p[h] * 0.25504366769049834f;    // (1/sqrt(32))*log2(e)*p[h]
  const unsigned short* KVl = KV + L*8;
  float4 qv = *(const float4*)(Qb + (size_t)node*128 + L*4);

  float a0=0.f, a1=0.f, a2=0.f, a3=0.f, den=0.f;
  int j = start;
  for (; j + 3 < end; j += 4){
    int s0 = srcs[j], s1 = srcs[j+1], s2 = srcs[j+2], s3 = srcs[j+3];
    uint4 kv0 = *(const uint4*)(KVl + (size_t)s0*256);
    uint4 kv1 = *(const uint4*)(KVl + (size_t)s1*256);
    uint4 kv2 = *(const uint4*)(KVl + (size_t)s2*256);
    uint4 kv3 = *(const uint4*)(KVl + (size_t)s3*256);
    float d0 = blo(kv0.x)*qv.x + bhi(kv0.x)*qv.y + blo(kv0.y)*qv.z + bhi(kv0.y)*qv.w;
    float d1 = blo(kv1.x)*qv.x + bhi(kv1.x)*qv.y + blo(kv1.y)*qv.z + bhi(kv1.y)*qv.w;
    float d2 = blo(kv2.x)*qv.x + bhi(kv2.x)*qv.y + blo(kv2.y)*qv.z + bhi(kv2.y)*qv.w;
    float d3 = blo(kv3.x)*qv.x + bhi(kv3.x)*qv.y + blo(kv3.y)*qv.z + bhi(kv3.y)*qv.w;
    #pragma unroll
    for (int m = 1; m < 8; m <<= 1){
      d0 += __shfl_xor(d0, m);
      d1 += __shfl_xor(d1, m);
      d2 += __shfl_xor(d2, m);
      d3 += __shfl_xor(d3, m);
    }
    float w0 = exp2f(d0 * ph);
    float w1 = exp2f(d1 * ph);
    float w2 = exp2f(d2 * ph);
    float w3 = exp2f(d3 * ph);
    den += (w0 + w1) + (w2 + w3);
    a0 += (w0*blo(kv0.z) + w1*blo(kv1.z)) + (w2*blo(kv2.z) + w3*blo(kv3.z));
    a1 += (w0*bhi(kv0.z) + w1*bhi(kv1.z)) + (w2*bhi(kv2.z) + w3*bhi(kv3.z));
    a2 += (w0*blo(kv0.w) + w1*blo(kv1.w)) + (w2*blo(kv2.w) + w3*blo(kv3.w));
    a3 += (w0*bhi(kv0.w) + w1*bhi(kv1.w)) + (w2*bhi(kv2.w) + w3*bhi(kv3.w));
  }
  for (; j < end; ++j){
    int s0 = srcs[j];
    uint4 kv0 = *(const uint4*)(KVl + (size_t)s0*256);
    float d0 = blo(kv0.x)*qv.x + bhi(kv0.x)*qv.y + blo(kv0.y)*qv.z + bhi(kv0.y)*qv.w;
    #pragma unroll
    for (int m = 1; m < 8; m <<= 1) d0 += __shfl_xor(d0, m);
    float w0 = exp2f(d0 * ph);
    den += w0;
    a0 += w0*blo(kv0.z);
    a1 += w0*bhi(kv0.z);
    a2 += w0*blo(kv0.w);
    a3 += w0*bhi(kv0.w);
  }
  float o[4] = {0.f, 0.f, 0.f, 0.f};
  if (end > start){
    float inv = 1.f / den;
    o[0] = gelu_exact(a0 * inv);
    o[1] = gelu_exact(a1 * inv);
    o[2] = gelu_exact(a2 * inv);
    o[3] = gelu_exact(a3 * inv);
  }
  // split hi/lo; 4 adjacent k-slots -> one 8B store per buffer (frag map = prep map)
  unsigned hh[4], ll[4];
  #pragma unroll
  for (int q = 0; q < 4; ++q){
    unsigned ub = __float_as_uint(o[q]);
    hh[q] = ub >> 16;
    ll[q] = __float_as_uint(o[q] - __uint_as_float(ub & 0xFFFF0000u)) >> 16;
  }
  size_t ci = (size_t)((node >> 4)*4 + h)*64 + (node & 15)*4 + ((L >> 1) & 3);
  size_t si = ci*8 + (L & 1)*4;
  uint2 uh = make_uint2(hh[0] | (hh[1] << 16), hh[2] | (hh[3] << 16));
  uint2 ul = make_uint2(ll[0] | (ll[1] << 16), ll[2] | (ll[3] << 16));
  *(uint2*)(fh + si) = uh;
  *(uint2*)(fl + si) = ul;
}

// ---------------- decoder ----------------
__global__ void k_gemv2(const float* __restrict__ z, const float* __restrict__ Wlp,
                        float* __restrict__ s1, float* __restrict__ s2, int NN){
  int n = blockIdx.x*256 + threadIdx.x;
  if (n >= NN) return;
  const float4* row = (const float4*)(z + (size_t)n*128);
  float a0 = 0.f, a1 = 0.f;
  #pragma unroll
  for (int i = 0; i < 32; ++i){
    float4 v  = row[i];
    float4 w1 = ((const float4*)Wlp)[i];
    float4 w2 = ((const float4*)Wlp)[32 + i];
    a0 += v.x*w1.x + v.y*w1.y + v.z*w1.z + v.w*w1.w;
    a1 += v.x*w2.x + v.y*w2.y + v.z*w2.z + v.w*w2.w;
  }
  s1[n] = a0; s2[n] = a1;
}

__global__ void k_decode(const int* __restrict__ pe, const int* __restrict__ ne,
                         const float* __restrict__ s1, const float* __restrict__ s2,
                         const float* __restrict__ blp, float* __restrict__ out, int P){
  int i = blockIdx.x*256 + threadIdx.x;
  if (i < P){
    out[i] = s1[pe[i]] + s2[pe[P + i]] + blp[0];
  } else if (i < 2*P){
    int j = i - P;
    out[P + j] = s1[ne[j]] + s2[ne[P + j]] + blp[0];
  }
}

extern "C" void kernel_launch(void* const* d_in, const int* in_sizes, int n_in,
                              void* d_out, int out_size, void* d_ws, size_t ws_size,
                              hipStream_t stream){
  const float* x      = (const float*)d_in[0];
  const int*   ei     = (const int*)d_in[1];
  const int*   pos_ei = (const int*)d_in[3];
  const int*   neg_ei = (const int*)d_in[4];
  const int NN = in_sizes[0] / 128;
  const int E  = in_sizes[1] / 2;
  const int P  = in_sizes[3] / 2;
  const int padM = CDIV(NN, 128) * 128;
  const int* e_src = ei;
  const int* e_dst = ei + E;

  char* wsb = (char*)d_ws;
  size_t off = 0;
  auto alloc = [&](size_t bytes)->char*{
    char* r = wsb + off;
    off = (off + bytes + 255) & ~(size_t)255;
    return r;
  };
  unsigned short* KV16 = (unsigned short*)alloc((size_t)NN*256*2);  // interleaved K/V quads
  float* Qb     = (float*)alloc((size_t)NN*128*4);
  float* h1     = (float*)alloc((size_t)NN*128*4);
  short* AfH    = (short*)alloc((size_t)padM*128*2);   // gelu(agg) frags from k_node
  short* AfL    = (short*)alloc((size_t)padM*128*2);
  int*   srcs   = (int*)alloc((size_t)E*4);
  int*   rowp   = (int*)alloc((size_t)(NN+1)*4);
  int*   deg    = (int*)alloc((size_t)NN*4);
  int*   cursor = (int*)alloc((size_t)NN*4);
  int*   partial= (int*)alloc(256*4);
  float* beffK  = (float*)alloc(128*4);
  float* beffV  = (float*)alloc(128*4);
  short* BfH    = (short*)alloc((size_t)4*16384*2);
  short* BfL    = (short*)alloc((size_t)4*16384*2);
  float* s1     = (float*)alloc((size_t)NN*4);
  float* s2     = (float*)alloc((size_t)NN*4);
  float* h2     = Qb;   // Qb dead after layer-2 k_node; layer-2 outgemm then writes it

  // ---- CSR (shared by both layers) ----
  const int nb = CDIV(NN, 256);     // 196 <= 256
  k_clear_int<<<CDIV(NN,256),256,0,stream>>>(deg, NN);
  k_deg<<<CDIV(E,256),256,0,stream>>>(e_dst, deg, E);
  k_scan_blk<<<nb,256,0,stream>>>(deg, rowp, partial, NN);
  k_scan_mid<<<1,256,0,stream>>>(partial, nb);
  k_scan_add<<<CDIV(NN,256),256,0,stream>>>(rowp, partial, cursor, NN, E);
  k_fill<<<CDIV(E,256),256,0,stream>>>(e_src, e_dst, cursor, srcs, E);

  const int gblk = padM / 128;
  auto layer = [&](const float* hin, float* hout, int base){
    const float* Wk  = (const float*)d_in[base+0];
    const float* bk  = (const float*)d_in[base+1];
    const float* Wq  = (const float*)d_in[base+2];
    const float* bq  = (const float*)d_in[base+3];
    const float* Wv  = (const float*)d_in[base+4];
    const float* bv  = (const float*)d_in[base+5];
    const float* a   = (const float*)d_in[base+6];
    const float* m   = (const float*)d_in[base+7];
    const float* p   = (const float*)d_in[base+8];
    const float* Wo  = (const float*)d_in[base+9];
    const float* bo  = (const float*)d_in[base+10];
    const float* sk  = (const float*)d_in[base+11];
    k_prep<<<CDIV(4*16384+256,256),256,0,stream>>>(Wk, bk, a, Wq, Wv, bv, m, Wo,
                                                   BfH, BfL, beffK, beffV);
    k_kqv<<<gblk,256,0,stream>>>(hin, BfH, BfL, beffK, bq, beffV, KV16, Qb, NN);
    k_node<<<CDIV(NN,8),256,0,stream>>>(KV16, Qb, srcs, rowp, p, AfH, AfL, NN);
    k_outgemm<<<gblk,256,0,stream>>>(AfH, AfL, BfH, BfL, bo, hin, sk, hout, NN);
  };
  layer(x,  h1, 5);
  layer(h1, h2, 17);

  k_gemv2<<<CDIV(NN,256),256,0,stream>>>(h2, (const float*)d_in[29], s1, s2, NN);
  k_decode<<<CDIV(2*P,256),256,0,stream>>>(pos_ei, neg_ei, s1, s2,
                                           (const float*)d_in[30], (float*)d_out, P);
}

// Round 15
// 359.443 us; speedup vs baseline: 1.8440x; 1.0747x over previous
//
#include <hip/hip_runtime.h>
#include <hip/hip_bf16.h>

#define CDIV(a,b) (((a)+(b)-1)/(b))

typedef __attribute__((ext_vector_type(8))) short bh8;     // 8 bf16 in 4 VGPRs
typedef __attribute__((ext_vector_type(4))) float f32x4;

__device__ __forceinline__ float gelu_exact(float x){
  return 0.5f * x * (1.0f + erff(x * 0.7071067811865475f));
}
__device__ __forceinline__ float blo(unsigned u){ return __uint_as_float(u << 16); }
__device__ __forceinline__ float bhi(unsigned u){ return __uint_as_float(u & 0xFFFF0000u); }
__device__ __forceinline__ unsigned short bf16bits(float x){
  __hip_bfloat16 b = __float2bfloat16(x);
  return *(unsigned short*)&b;
}

// ---------------- CSR build ----------------
__global__ void k_clear_int(int* __restrict__ p, int n){
  int i = blockIdx.x*256 + threadIdx.x;
  if (i < n) p[i] = 0;
}

__global__ void k_deg(const int* __restrict__ dst, int* __restrict__ deg, int E){
  int e = blockIdx.x*256 + threadIdx.x;
  if (e < E) atomicAdd(&deg[dst[e]], 1);
}

// ---- hierarchical scan: per-block exclusive scan + partials ----
__global__ void k_scan_blk(const int* __restrict__ deg, int* __restrict__ rowp,
                           int* __restrict__ partial, int N){
  __shared__ int buf[256];
  int i = blockIdx.x*256 + threadIdx.x;
  int v = (i < N) ? deg[i] : 0;
  buf[threadIdx.x] = v;
  __syncthreads();
  #pragma unroll
  for (int off = 1; off < 256; off <<= 1){
    int t = (threadIdx.x >= off) ? buf[threadIdx.x - off] : 0;
    __syncthreads();
    buf[threadIdx.x] += t;
    __syncthreads();
  }
  if (i < N) rowp[i] = buf[threadIdx.x] - v;        // exclusive within block
  if (threadIdx.x == 255) partial[blockIdx.x] = buf[255];
}

// single block: exclusive scan of partials (nb <= 256)
__global__ void k_scan_mid(int* __restrict__ partial, int nb){
  __shared__ int buf[256];
  int v = (threadIdx.x < nb) ? partial[threadIdx.x] : 0;
  buf[threadIdx.x] = v;
  __syncthreads();
  #pragma unroll
  for (int off = 1; off < 256; off <<= 1){
    int t = (threadIdx.x >= off) ? buf[threadIdx.x - off] : 0;
    __syncthreads();
    buf[threadIdx.x] += t;
    __syncthreads();
  }
  if (threadIdx.x < nb) partial[threadIdx.x] = buf[threadIdx.x] - v;  // exclusive
}

// adds block offsets; also emits cursor copy
__global__ void k_scan_add(int* __restrict__ rowp, const int* __restrict__ partial,
                           int* __restrict__ cursor, int N, int E){
  int i = blockIdx.x*256 + threadIdx.x;
  if (i < N){
    int v = rowp[i] + partial[i >> 8];
    rowp[i] = v;
    cursor[i] = v;
  }
  if (i == 0) rowp[N] = E;
}

__global__ void k_fill(const int* __restrict__ src, const int* __restrict__ dst,
                       int* __restrict__ cursor, int* __restrict__ srcs, int E){
  int e = blockIdx.x*256 + threadIdx.x;
  if (e >= E) return;
  int d = dst[e];
  int pos = atomicAdd(&cursor[d], 1);
  srcs[pos] = src[e];
}

// -------- fused weight prep: rel-fold + transpose + hi/lo split into MFMA frag order --------
// groups: 0=K (fused Ak), 1=Q, 2=V (fused Av), 3=O. Also computes beffK/beffV.
__global__ void k_prep(const float* __restrict__ Wk, const float* __restrict__ bk,
                       const float* __restrict__ Ak, const float* __restrict__ Wq,
                       const float* __restrict__ Wv, const float* __restrict__ bv,
                       const float* __restrict__ Av, const float* __restrict__ Wo,
                       short* __restrict__ BfH, short* __restrict__ BfL,
                       float* __restrict__ beffK, float* __restrict__ beffV){
  int t = blockIdx.x*256 + threadIdx.x;
  if (t < 4*16384){
    int g = t >> 14;
    int u = t & 16383;
    int k = u & 127, n = u >> 7;
    float x;
    if (g == 1)      x = Wq[(size_t)k*128 + n];
    else if (g == 3) x = Wo[(size_t)k*128 + n];
    else {
      const float* W = (g == 0) ? Wk : Wv;
      const float* A = (g == 0) ? Ak : Av;
      int h = n >> 5, e2 = n & 31;
      const float* s  = W + (size_t)k*128 + h*32;
      const float* Ah = A + h*1024 + e2;
      float acc = 0.f;
      #pragma unroll
      for (int d = 0; d < 32; ++d) acc += s[d] * Ah[d*32];
      x = acc;
    }
    unsigned ub = __float_as_uint(x);
    short hi = (short)(ub >> 16);
    float fh = __uint_as_float(ub & 0xFFFF0000u);
    short lo = (short)(__float_as_uint(x - fh) >> 16);
    int nt = n >> 4, lr = n & 15, ks = k >> 5, lk = (k >> 3) & 3, e = k & 7;
    size_t o = ((size_t)((g*8 + nt)*4 + ks)*64 + lr*4 + lk)*8 + e;
    BfH[o] = hi;
    BfL[o] = lo;
  } else {
    int u = t - 4*16384;       // 0..255: effective biases
    if (u < 256){
      int which = u >> 7, n = u & 127;
      const float* b = which ? bv : bk;
      const float* A = which ? Av : Ak;
      int h = n >> 5, e2 = n & 31;
      const float* Ah = A + h*1024 + e2;
      float acc = 0.f;
      #pragma unroll
      for (int d = 0; d < 32; ++d) acc += b[h*32 + d] * Ah[d*32];
      (which ? beffV : beffK)[n] = acc;
    }
  }
}

// ---------------- fused K/Q/V GEMM, SWAPPED operands: lane owns one node-row, 4 consecutive channels ----------------
// acc = mfma(Bfrag, Afrag): lane l holds C[chan = nt*16 + lk*4 + i][node = panel*16 + lr]
// -> vectorized epilogue: K-quad/V-quad 8B stores, Q float4 stores. Bit-identical math.
__global__ __launch_bounds__(256)
void k_kqv(const float* __restrict__ A,
           const short* __restrict__ BfH, const short* __restrict__ BfL,
           const float* __restrict__ bK, const float* __restrict__ bQ,
           const float* __restrict__ bV,
           unsigned short* __restrict__ KV16, float* __restrict__ Qo, int M){
  const int tid = threadIdx.x;
  const int wm = tid >> 6, l = tid & 63;
  const int lr = l & 15, lk = l >> 4;
  const int perm = (lr*4 + lk)*8;
  const int p0 = blockIdx.x*8 + wm*2;

  bh8 a_h[2][4], a_l[2][4];
  #pragma unroll
  for (int p = 0; p < 2; ++p){
    int row = (p0 + p)*16 + lr;
    #pragma unroll
    for (int ks = 0; ks < 4; ++ks){
      float f[8] = {0.f,0.f,0.f,0.f,0.f,0.f,0.f,0.f};
      if (row < M){
        float4 va = *(const float4*)(A + (size_t)row*128 + ks*32 + lk*8);
        float4 vb = *(const float4*)(A + (size_t)row*128 + ks*32 + lk*8 + 4);
        f[0]=va.x; f[1]=va.y; f[2]=va.z; f[3]=va.w;
        f[4]=vb.x; f[5]=vb.y; f[6]=vb.z; f[7]=vb.w;
      }
      bh8 h8, l8;
      #pragma unroll
      for (int q = 0; q < 8; ++q){
        unsigned ub = __float_as_uint(f[q]);
        h8[q] = (short)(ub >> 16);
        float fhv = __uint_as_float(ub & 0xFFFF0000u);
        l8[q] = (short)(__float_as_uint(f[q] - fhv) >> 16);
      }
      a_h[p][ks] = h8;
      a_l[p][ks] = l8;
    }
  }

  #pragma unroll
  for (int g = 0; g < 3; ++g){
    f32x4 acc[2][8];
    #pragma unroll
    for (int p = 0; p < 2; ++p)
      #pragma unroll
      for (int i = 0; i < 8; ++i) acc[p][i] = (f32x4){0.f,0.f,0.f,0.f};
    #pragma unroll
    for (int ks = 0; ks < 4; ++ks){
      #pragma unroll
      for (int nt = 0; nt < 8; ++nt){
        size_t o = (size_t)((g*8 + nt)*4 + ks)*512 + perm;
        bh8 bh_ = *(const bh8*)(BfH + o);
        bh8 bl_ = *(const bh8*)(BfL + o);
        #pragma unroll
        for (int p = 0; p < 2; ++p){
          acc[p][nt] = __builtin_amdgcn_mfma_f32_16x16x32_bf16(bh_, a_h[p][ks], acc[p][nt], 0, 0, 0);
          acc[p][nt] = __builtin_amdgcn_mfma_f32_16x16x32_bf16(bh_, a_l[p][ks], acc[p][nt], 0, 0, 0);
          acc[p][nt] = __builtin_amdgcn_mfma_f32_16x16x32_bf16(bl_, a_h[p][ks], acc[p][nt], 0, 0, 0);
        }
      }
    }
    const float* bias = (g==0) ? bK : (g==1) ? bQ : bV;
    #pragma unroll
    for (int p = 0; p < 2; ++p){
      int r = (p0 + p)*16 + lr;
      if (r >= M) continue;
      #pragma unroll
      for (int nt = 0; nt < 8; ++nt){
        int c0 = nt*16 + lk*4;
        float4 bs = *(const float4*)(bias + c0);
        float v0 = acc[p][nt][0] + bs.x;
        float v1 = acc[p][nt][1] + bs.y;
        float v2 = acc[p][nt][2] + bs.z;
        float v3 = acc[p][nt][3] + bs.w;
        if (g == 1){
          *(float4*)(Qo + (size_t)r*128 + c0) = make_float4(v0, v1, v2, v3);
        } else {
          unsigned u0 = (unsigned)bf16bits(v0) | ((unsigned)bf16bits(v1) << 16);
          unsigned u1 = (unsigned)bf16bits(v2) | ((unsigned)bf16bits(v3) << 16);
          *(uint2*)(KV16 + (size_t)r*256 + (size_t)(nt*4 + lk)*8 + ((g == 2) ? 4 : 0))
              = make_uint2(u0, u1);
        }
      }
    }
  }
}

// ---------------- out GEMM (swapped): h = sg*(gelu(agg)@Wo + bo) + (1-sg)*hin ----------------
__global__ __launch_bounds__(256)
void k_outgemm(const short* __restrict__ AfH, const short* __restrict__ AfL,
               const short* __restrict__ BfH, const short* __restrict__ BfL,
               const float* __restrict__ bias, const float* __restrict__ mixsrc,
               const float* __restrict__ skipp, float* __restrict__ out, int M){
  const int tid = threadIdx.x;
  const int wm = tid >> 6, l = tid & 63;
  const int lr = l & 15, lk = l >> 4;
  const int perm = (lr*4 + lk)*8;
  const int p0 = blockIdx.x*8 + wm*2;

  bh8 a_h[2][4], a_l[2][4];
  #pragma unroll
  for (int p = 0; p < 2; ++p)
    #pragma unroll
    for (int ks = 0; ks < 4; ++ks){
      size_t o = (size_t)((p0 + p)*4 + ks)*512 + perm;
      a_h[p][ks] = *(const bh8*)(AfH + o);
      a_l[p][ks] = *(const bh8*)(AfL + o);
    }

  f32x4 acc[2][8];
  #pragma unroll
  for (int p = 0; p < 2; ++p)
    #pragma unroll
    for (int i = 0; i < 8; ++i) acc[p][i] = (f32x4){0.f,0.f,0.f,0.f};
  #pragma unroll
  for (int ks = 0; ks < 4; ++ks){
    #pragma unroll
    for (int nt = 0; nt < 8; ++nt){
      size_t o = (size_t)((3*8 + nt)*4 + ks)*512 + perm;
      bh8 bh_ = *(const bh8*)(BfH + o);
      bh8 bl_ = *(const bh8*)(BfL + o);
      #pragma unroll
      for (int p = 0; p < 2; ++p){
        acc[p][nt] = __builtin_amdgcn_mfma_f32_16x16x32_bf16(bh_, a_h[p][ks], acc[p][nt], 0, 0, 0);
        acc[p][nt] = __builtin_amdgcn_mfma_f32_16x16x32_bf16(bh_, a_l[p][ks], acc[p][nt], 0, 0, 0);
        acc[p][nt] = __builtin_amdgcn_mfma_f32_16x16x32_bf16(bl_, a_h[p][ks], acc[p][nt], 0, 0, 0);
      }
    }
  }
  float sg = 1.f / (1.f + expf(-skipp[0]));
  #pragma unroll
  for (int p = 0; p < 2; ++p){
    int r = (p0 + p)*16 + lr;
    if (r >= M) continue;
    #pragma unroll
    for (int nt = 0; nt < 8; ++nt){
      int c0 = nt*16 + lk*4;
      float4 bs  = *(const float4*)(bias + c0);
      float4 mx  = *(const float4*)(mixsrc + (size_t)r*128 + c0);
      float4 o4;
      o4.x = sg*(acc[p][nt][0] + bs.x) + (1.f - sg)*mx.x;
      o4.y = sg*(acc[p][nt][1] + bs.y) + (1.f - sg)*mx.y;
      o4.z = sg*(acc[p][nt][2] + bs.z) + (1.f - sg)*mx.z;
      o4.w = sg*(acc[p][nt][3] + bs.w) + (1.f - sg)*mx.w;
      *(float4*)(out + (size_t)r*128 + c0) = o4;
    }
  }
}

// ---------------- fused attention: 2 nodes per wave, unroll-4 (8 edges in flight/wave) ----------------
// Half-wave owns one node; L=lane&31 owns channels 4L..4L+3; head h=L>>3 (8-lane groups,
// 3-shfl reduce). One 16B gather per edge per lane (K-quad + V-quad). No max-shift.
__global__ __launch_bounds__(256)
void k_node(const unsigned short* __restrict__ KV, const float* __restrict__ Qb,
            const int* __restrict__ srcs, const int* __restrict__ row_ptr,
            const float* __restrict__ p,
            short* __restrict__ fh, short* __restrict__ fl, int NN){
  int wave = threadIdx.x >> 6;
  int lane = threadIdx.x & 63;
  int L = lane & 31;
  int node = blockIdx.x*8 + wave*2 + (lane >> 5);
  if (node >= NN) return;
  int start = row_ptr[node], end = row_ptr[node+1];
  int h = L >> 3;
  float ph = p[h] * 0.25504366769049834f;    // (1/sqrt(32))*log2(e)*p[h]
  const unsigned short* KVl = KV + L*8;
  float4 qv = *(const float4*)(Qb + (size_t)node*128 + L*4);

  float a0=0.f, a1=0.f, a2=0.f, a3=0.f, den=0.f;
  int j = start;
  for (; j + 3 < end; j += 4){
    int s0 = srcs[j], s1 = srcs[j+1], s2 = srcs[j+2], s3 = srcs[j+3];
    uint4 kv0 = *(const uint4*)(KVl + (size_t)s0*256);
    uint4 kv1 = *(const uint4*)(KVl + (size_t)s1*256);
    uint4 kv2 = *(const uint4*)(KVl + (size_t)s2*256);
    uint4 kv3 = *(const uint4*)(KVl + (size_t)s3*256);
    float d0 = blo(kv0.x)*qv.x + bhi(kv0.x)*qv.y + blo(kv0.y)*qv.z + bhi(kv0.y)*qv.w;
    float d1 = blo(kv1.x)*qv.x + bhi(kv1.x)*qv.y + blo(kv1.y)*qv.z + bhi(kv1.y)*qv.w;
    float d2 = blo(kv2.x)*qv.x + bhi(kv2.x)*qv.y + blo(kv2.y)*qv.z + bhi(kv2.y)*qv.w;
    float d3 = blo(kv3.x)*qv.x + bhi(kv3.x)*qv.y + blo(kv3.y)*qv.z + bhi(kv3.y)*qv.w;
    #pragma unroll
    for (int m = 1; m < 8; m <<= 1){
      d0 += __shfl_xor(d0, m);
      d1 += __shfl_xor(d1, m);
      d2 += __shfl_xor(d2, m);
      d3 += __shfl_xor(d3, m);
    }
    float w0 = exp2f(d0 * ph);
    float w1 = exp2f(d1 * ph);
    float w2 = exp2f(d2 * ph);
    float w3 = exp2f(d3 * ph);
    den += (w0 + w1) + (w2 + w3);
    a0 += (w0*blo(kv0.z) + w1*blo(kv1.z)) + (w2*blo(kv2.z) + w3*blo(kv3.z));
    a1 += (w0*bhi(kv0.z) + w1*bhi(kv1.z)) + (w2*bhi(kv2.z) + w3*bhi(kv3.z));
    a2 += (w0*blo(kv0.w) + w1*blo(kv1.w)) + (w2*blo(kv2.w) + w3*blo(kv3.w));
    a3 += (w0*bhi(kv0.w) + w1*bhi(kv1.w)) + (w2*bhi(kv2.w) + w3*bhi(kv3.w));
  }
  for (; j < end; ++j){
    int s0 = srcs[j];
    uint4 kv0 = *(const uint4*)(KVl + (size_t)s0*256);
    float d0 = blo(kv0.x)*qv.x + bhi(kv0.x)*qv.y + blo(kv0.y)*qv.z + bhi(kv0.y)*qv.w;
    #pragma unroll
    for (int m = 1; m < 8; m <<= 1) d0 += __shfl_xor(d0, m);
    float w0 = exp2f(d0 * ph);
    den += w0;
    a0 += w0*blo(kv0.z);
    a1 += w0*bhi(kv0.z);
    a2 += w0*blo(kv0.w);
    a3 += w0*bhi(kv0.w);
  }
  float o[4] = {0.f, 0.f, 0.f, 0.f};
  if (end > start){
    float inv = 1.f / den;
    o[0] = gelu_exact(a0 * inv);
    o[1] = gelu_exact(a1 * inv);
    o[2] = gelu_exact(a2 * inv);
    o[3] = gelu_exact(a3 * inv);
  }
  // split hi/lo; 4 adjacent k-slots -> one 8B store per buffer (frag map = prep map)
  unsigned hh[4], ll[4];
  #pragma unroll
  for (int q = 0; q < 4; ++q){
    unsigned ub = __float_as_uint(o[q]);
    hh[q] = ub >> 16;
    ll[q] = __float_as_uint(o[q] - __uint_as_float(ub & 0xFFFF0000u)) >> 16;
  }
  size_t ci = (size_t)((node >> 4)*4 + h)*64 + (node & 15)*4 + ((L >> 1) & 3);
  size_t si = ci*8 + (L & 1)*4;
  uint2 uh = make_uint2(hh[0] | (hh[1] << 16), hh[2] | (hh[3] << 16));
  uint2 ul = make_uint2(ll[0] | (ll[1] << 16), ll[2] | (ll[3] << 16));
  *(uint2*)(fh + si) = uh;
  *(uint2*)(fl + si) = ul;
}

// ---------------- decoder ----------------
__global__ void k_gemv2(const float* __restrict__ z, const float* __restrict__ Wlp,
                        float* __restrict__ s1, float* __restrict__ s2, int NN){
  int n = blockIdx.x*256 + threadIdx.x;
  if (n >= NN) return;
  const float4* row = (const float4*)(z + (size_t)n*128);
  float a0 = 0.f, a1 = 0.f;
  #pragma unroll
  for (int i = 0; i < 32; ++i){
    float4 v  = row[i];
    float4 w1 = ((const float4*)Wlp)[i];
    float4 w2 = ((const float4*)Wlp)[32 + i];
    a0 += v.x*w1.x + v.y*w1.y + v.z*w1.z + v.w*w1.w;
    a1 += v.x*w2.x + v.y*w2.y + v.z*w2.z + v.w*w2.w;
  }
  s1[n] = a0; s2[n] = a1;
}

__global__ void k_decode(const int* __restrict__ pe, const int* __restrict__ ne,
                         const float* __restrict__ s1, const float* __restrict__ s2,
                         const float* __restrict__ blp, float* __restrict__ out, int P){
  int i = blockIdx.x*256 + threadIdx.x;
  if (i < P){
    out[i] = s1[pe[i]] + s2[pe[P + i]] + blp[0];
  } else if (i < 2*P){
    int j = i - P;
    out[P + j] = s1[ne[j]] + s2[ne[P + j]] + blp[0];
  }
}

extern "C" void kernel_launch(void* const* d_in, const int* in_sizes, int n_in,
                              void* d_out, int out_size, void* d_ws, size_t ws_size,
                              hipStream_t stream){
  const float* x      = (const float*)d_in[0];
  const int*   ei     = (const int*)d_in[1];
  const int*   pos_ei = (const int*)d_in[3];
  const int*   neg_ei = (const int*)d_in[4];
  const int NN = in_sizes[0] / 128;
  const int E  = in_sizes[1] / 2;
  const int P  = in_sizes[3] / 2;
  const int padM = CDIV(NN, 128) * 128;
  const int* e_src = ei;
  const int* e_dst = ei + E;

  char* wsb = (char*)d_ws;
  size_t off = 0;
  auto alloc = [&](size_t bytes)->char*{
    char* r = wsb + off;
    off = (off + bytes + 255) & ~(size_t)255;
    return r;
  };
  unsigned short* KV16 = (unsigned short*)alloc((size_t)NN*256*2);  // interleaved K/V quads
  float* Qb     = (float*)alloc((size_t)NN*128*4);
  float* h1     = (float*)alloc((size_t)NN*128*4);
  short* AfH    = (short*)alloc((size_t)padM*128*2);   // gelu(agg) frags from k_node
  short* AfL    = (short*)alloc((size_t)padM*128*2);
  int*   srcs   = (int*)alloc((size_t)E*4);
  int*   rowp   = (int*)alloc((size_t)(NN+1)*4);
  int*   deg    = (int*)alloc((size_t)NN*4);
  int*   cursor = (int*)alloc((size_t)NN*4);
  int*   partial= (int*)alloc(256*4);
  float* beffK  = (float*)alloc(128*4);
  float* beffV  = (float*)alloc(128*4);
  short* BfH    = (short*)alloc((size_t)4*16384*2);
  short* BfL    = (short*)alloc((size_t)4*16384*2);
  float* s1     = (float*)alloc((size_t)NN*4);
  float* s2     = (float*)alloc((size_t)NN*4);
  float* h2     = Qb;   // Qb dead after layer-2 k_node; layer-2 outgemm then writes it

  // ---- CSR (shared by both layers) ----
  const int nb = CDIV(NN, 256);     // 196 <= 256
  k_clear_int<<<CDIV(NN,256),256,0,stream>>>(deg, NN);
  k_deg<<<CDIV(E,256),256,0,stream>>>(e_dst, deg, E);
  k_scan_blk<<<nb,256,0,stream>>>(deg, rowp, partial, NN);
  k_scan_mid<<<1,256,0,stream>>>(partial, nb);
  k_scan_add<<<CDIV(NN,256),256,0,stream>>>(rowp, partial, cursor, NN, E);
  k_fill<<<CDIV(E,256),256,0,stream>>>(e_src, e_dst, cursor, srcs, E);

  const int gblk = padM / 128;
  auto layer = [&](const float* hin, float* hout, int base){
    const float* Wk  = (const float*)d_in[base+0];
    const float* bk  = (const float*)d_in[base+1];
    const float* Wq  = (const float*)d_in[base+2];
    const float* bq  = (const float*)d_in[base+3];
    const float* Wv  = (const float*)d_in[base+4];
    const float* bv  = (const float*)d_in[base+5];
    const float* a   = (const float*)d_in[base+6];
    const float* m   = (const float*)d_in[base+7];
    const float* p   = (const float*)d_in[base+8];
    const float* Wo  = (const float*)d_in[base+9];
    const float* bo  = (const float*)d_in[base+10];
    const float* sk  = (const float*)d_in[base+11];
    k_prep<<<CDIV(4*16384+256,256),256,0,stream>>>(Wk, bk, a, Wq, Wv, bv, m, Wo,
                                                   BfH, BfL, beffK, beffV);
    k_kqv<<<gblk,256,0,stream>>>(hin, BfH, BfL, beffK, bq, beffV, KV16, Qb, NN);
    k_node<<<CDIV(NN,8),256,0,stream>>>(KV16, Qb, srcs, rowp, p, AfH, AfL, NN);
    k_outgemm<<<gblk,256,0,stream>>>(AfH, AfL, BfH, BfL, bo, hin, sk, hout, NN);
  };
  layer(x,  h1, 5);
  layer(h1, h2, 17);

  k_gemv2<<<CDIV(NN,256),256,0,stream>>>(h2, (const float*)d_in[29], s1, s2, NN);
  k_decode<<<CDIV(2*P,256),256,0,stream>>>(pos_ei, neg_ei, s1, s2,
                                           (const float*)d_in[30], (float*)d_out, P);
}

// Round 16
// 335.866 us; speedup vs baseline: 1.9735x; 1.0702x over previous
//
#include <hip/hip_runtime.h>
#include <hip/hip_bf16.h>

#define CDIV(a,b) (((a)+(b)-1)/(b))

typedef __attribute__((ext_vector_type(8))) short bh8;     // 8 bf16 in 4 VGPRs
typedef __attribute__((ext_vector_type(4))) float f32x4;

__device__ __forceinline__ float gelu_exact(float x){
  return 0.5f * x * (1.0f + erff(x * 0.7071067811865475f));
}
__device__ __forceinline__ float blo(unsigned u){ return __uint_as_float(u << 16); }
__device__ __forceinline__ float bhi(unsigned u){ return __uint_as_float(u & 0xFFFF0000u); }
__device__ __forceinline__ unsigned short bf16bits(float x){
  __hip_bfloat16 b = __float2bfloat16(x);
  return *(unsigned short*)&b;
}

// ---------------- CSR build ----------------
__global__ void k_clear_int(int* __restrict__ p, int n){
  int i = blockIdx.x*256 + threadIdx.x;
  if (i < n) p[i] = 0;
}

__global__ void k_deg(const int* __restrict__ dst, int* __restrict__ deg, int E){
  int e = blockIdx.x*256 + threadIdx.x;
  if (e < E) atomicAdd(&deg[dst[e]], 1);
}

// ---- hierarchical scan: per-block exclusive scan + partials ----
__global__ void k_scan_blk(const int* __restrict__ deg, int* __restrict__ rowp,
                           int* __restrict__ partial, int N){
  __shared__ int buf[256];
  int i = blockIdx.x*256 + threadIdx.x;
  int v = (i < N) ? deg[i] : 0;
  buf[threadIdx.x] = v;
  __syncthreads();
  #pragma unroll
  for (int off = 1; off < 256; off <<= 1){
    int t = (threadIdx.x >= off) ? buf[threadIdx.x - off] : 0;
    __syncthreads();
    buf[threadIdx.x] += t;
    __syncthreads();
  }
  if (i < N) rowp[i] = buf[threadIdx.x] - v;        // exclusive within block
  if (threadIdx.x == 255) partial[blockIdx.x] = buf[255];
}

// single block: exclusive scan of partials (nb <= 256)
__global__ void k_scan_mid(int* __restrict__ partial, int nb){
  __shared__ int buf[256];
  int v = (threadIdx.x < nb) ? partial[threadIdx.x] : 0;
  buf[threadIdx.x] = v;
  __syncthreads();
  #pragma unroll
  for (int off = 1; off < 256; off <<= 1){
    int t = (threadIdx.x >= off) ? buf[threadIdx.x - off] : 0;
    __syncthreads();
    buf[threadIdx.x] += t;
    __syncthreads();
  }
  if (threadIdx.x < nb) partial[threadIdx.x] = buf[threadIdx.x] - v;  // exclusive
}

// adds block offsets; also emits cursor copy
__global__ void k_scan_add(int* __restrict__ rowp, const int* __restrict__ partial,
                           int* __restrict__ cursor, int N, int E){
  int i = blockIdx.x*256 + threadIdx.x;
  if (i < N){
    int v = rowp[i] + partial[i >> 8];
    rowp[i] = v;
    cursor[i] = v;
  }
  if (i == 0) rowp[N] = E;
}

__global__ void k_fill(const int* __restrict__ src, const int* __restrict__ dst,
                       int* __restrict__ cursor, int* __restrict__ srcs, int E){
  int e = blockIdx.x*256 + threadIdx.x;
  if (e >= E) return;
  int d = dst[e];
  int pos = atomicAdd(&cursor[d], 1);
  srcs[pos] = src[e];
}

// -------- fused weight prep: rel-fold + transpose + hi/lo split into MFMA frag order --------
// groups: 0=K (fused Ak), 1=Q, 2=V (fused Av), 3=O. Also computes beffK/beffV.
__global__ void k_prep(const float* __restrict__ Wk, const float* __restrict__ bk,
                       const float* __restrict__ Ak, const float* __restrict__ Wq,
                       const float* __restrict__ Wv, const float* __restrict__ bv,
                       const float* __restrict__ Av, const float* __restrict__ Wo,
                       short* __restrict__ BfH, short* __restrict__ BfL,
                       float* __restrict__ beffK, float* __restrict__ beffV){
  int t = blockIdx.x*256 + threadIdx.x;
  if (t < 4*16384){
    int g = t >> 14;
    int u = t & 16383;
    int k = u & 127, n = u >> 7;
    float x;
    if (g == 1)      x = Wq[(size_t)k*128 + n];
    else if (g == 3) x = Wo[(size_t)k*128 + n];
    else {
      const float* W = (g == 0) ? Wk : Wv;
      const float* A = (g == 0) ? Ak : Av;
      int h = n >> 5, e2 = n & 31;
      const float* s  = W + (size_t)k*128 + h*32;
      const float* Ah = A + h*1024 + e2;
      float acc = 0.f;
      #pragma unroll
      for (int d = 0; d < 32; ++d) acc += s[d] * Ah[d*32];
      x = acc;
    }
    unsigned ub = __float_as_uint(x);
    short hi = (short)(ub >> 16);
    float fh = __uint_as_float(ub & 0xFFFF0000u);
    short lo = (short)(__float_as_uint(x - fh) >> 16);
    int nt = n >> 4, lr = n & 15, ks = k >> 5, lk = (k >> 3) & 3, e = k & 7;
    size_t o = ((size_t)((g*8 + nt)*4 + ks)*64 + lr*4 + lk)*8 + e;
    BfH[o] = hi;
    BfL[o] = lo;
  } else {
    int u = t - 4*16384;       // 0..255: effective biases
    if (u < 256){
      int which = u >> 7, n = u & 127;
      const float* b = which ? bv : bk;
      const float* A = which ? Av : Ak;
      int h = n >> 5, e2 = n & 31;
      const float* Ah = A + h*1024 + e2;
      float acc = 0.f;
      #pragma unroll
      for (int d = 0; d < 32; ++d) acc += b[h*32 + d] * Ah[d*32];
      (which ? beffV : beffK)[n] = acc;
    }
  }
}

// ---------------- fused K/Q/V GEMM, swapped operands, 2-term split ----------------
// K/Q/V outputs are all bf16 (stored rounding ~ dropped-term error), so drop the
// B-lo term: acc = bh*ah + bh*al. No BfL loads at all. Lane owns one node-row,
// 4 consecutive channels -> vectorized 8B stores.
__global__ __launch_bounds__(256)
void k_kqv(const float* __restrict__ A,
           const short* __restrict__ BfH,
           const float* __restrict__ bK, const float* __restrict__ bQ,
           const float* __restrict__ bV,
           unsigned short* __restrict__ KV16, unsigned short* __restrict__ Qb16, int M){
  const int tid = threadIdx.x;
  const int wm = tid >> 6, l = tid & 63;
  const int lr = l & 15, lk = l >> 4;
  const int perm = (lr*4 + lk)*8;
  const int p0 = blockIdx.x*8 + wm*2;

  bh8 a_h[2][4], a_l[2][4];
  #pragma unroll
  for (int p = 0; p < 2; ++p){
    int row = (p0 + p)*16 + lr;
    #pragma unroll
    for (int ks = 0; ks < 4; ++ks){
      float f[8] = {0.f,0.f,0.f,0.f,0.f,0.f,0.f,0.f};
      if (row < M){
        float4 va = *(const float4*)(A + (size_t)row*128 + ks*32 + lk*8);
        float4 vb = *(const float4*)(A + (size_t)row*128 + ks*32 + lk*8 + 4);
        f[0]=va.x; f[1]=va.y; f[2]=va.z; f[3]=va.w;
        f[4]=vb.x; f[5]=vb.y; f[6]=vb.z; f[7]=vb.w;
      }
      bh8 h8, l8;
      #pragma unroll
      for (int q = 0; q < 8; ++q){
        unsigned ub = __float_as_uint(f[q]);
        h8[q] = (short)(ub >> 16);
        float fhv = __uint_as_float(ub & 0xFFFF0000u);
        l8[q] = (short)(__float_as_uint(f[q] - fhv) >> 16);
      }
      a_h[p][ks] = h8;
      a_l[p][ks] = l8;
    }
  }

  #pragma unroll
  for (int g = 0; g < 3; ++g){
    f32x4 acc[2][8];
    #pragma unroll
    for (int p = 0; p < 2; ++p)
      #pragma unroll
      for (int i = 0; i < 8; ++i) acc[p][i] = (f32x4){0.f,0.f,0.f,0.f};
    #pragma unroll
    for (int ks = 0; ks < 4; ++ks){
      #pragma unroll
      for (int nt = 0; nt < 8; ++nt){
        size_t o = (size_t)((g*8 + nt)*4 + ks)*512 + perm;
        bh8 bh_ = *(const bh8*)(BfH + o);
        #pragma unroll
        for (int p = 0; p < 2; ++p){
          acc[p][nt] = __builtin_amdgcn_mfma_f32_16x16x32_bf16(bh_, a_h[p][ks], acc[p][nt], 0, 0, 0);
          acc[p][nt] = __builtin_amdgcn_mfma_f32_16x16x32_bf16(bh_, a_l[p][ks], acc[p][nt], 0, 0, 0);
        }
      }
    }
    const float* bias = (g==0) ? bK : (g==1) ? bQ : bV;
    #pragma unroll
    for (int p = 0; p < 2; ++p){
      int r = (p0 + p)*16 + lr;
      if (r >= M) continue;
      #pragma unroll
      for (int nt = 0; nt < 8; ++nt){
        int c0 = nt*16 + lk*4;
        float4 bs = *(const float4*)(bias + c0);
        float v0 = acc[p][nt][0] + bs.x;
        float v1 = acc[p][nt][1] + bs.y;
        float v2 = acc[p][nt][2] + bs.z;
        float v3 = acc[p][nt][3] + bs.w;
        unsigned u0 = (unsigned)bf16bits(v0) | ((unsigned)bf16bits(v1) << 16);
        unsigned u1 = (unsigned)bf16bits(v2) | ((unsigned)bf16bits(v3) << 16);
        if (g == 1){
          *(uint2*)(Qb16 + (size_t)r*128 + c0) = make_uint2(u0, u1);
        } else {
          *(uint2*)(KV16 + (size_t)r*256 + (size_t)(nt*4 + lk)*8 + ((g == 2) ? 4 : 0))
              = make_uint2(u0, u1);
        }
      }
    }
  }
}

// ---------------- out GEMM (swapped, full 3-term): h = sg*(gelu(agg)@Wo + bo) + (1-sg)*hin ----------------
__global__ __launch_bounds__(256)
void k_outgemm(const short* __restrict__ AfH, const short* __restrict__ AfL,
               const short* __restrict__ BfH, const short* __restrict__ BfL,
               const float* __restrict__ bias, const float* __restrict__ mixsrc,
               const float* __restrict__ skipp, float* __restrict__ out, int M){
  const int tid = threadIdx.x;
  const int wm = tid >> 6, l = tid & 63;
  const int lr = l & 15, lk = l >> 4;
  const int perm = (lr*4 + lk)*8;
  const int p0 = blockIdx.x*8 + wm*2;

  bh8 a_h[2][4], a_l[2][4];
  #pragma unroll
  for (int p = 0; p < 2; ++p)
    #pragma unroll
    for (int ks = 0; ks < 4; ++ks){
      size_t o = (size_t)((p0 + p)*4 + ks)*512 + perm;
      a_h[p][ks] = *(const bh8*)(AfH + o);
      a_l[p][ks] = *(const bh8*)(AfL + o);
    }

  f32x4 acc[2][8];
  #pragma unroll
  for (int p = 0; p < 2; ++p)
    #pragma unroll
    for (int i = 0; i < 8; ++i) acc[p][i] = (f32x4){0.f,0.f,0.f,0.f};
  #pragma unroll
  for (int ks = 0; ks < 4; ++ks){
    #pragma unroll
    for (int nt = 0; nt < 8; ++nt){
      size_t o = (size_t)((3*8 + nt)*4 + ks)*512 + perm;
      bh8 bh_ = *(const bh8*)(BfH + o);
      bh8 bl_ = *(const bh8*)(BfL + o);
      #pragma unroll
      for (int p = 0; p < 2; ++p){
        acc[p][nt] = __builtin_amdgcn_mfma_f32_16x16x32_bf16(bh_, a_h[p][ks], acc[p][nt], 0, 0, 0);
        acc[p][nt] = __builtin_amdgcn_mfma_f32_16x16x32_bf16(bh_, a_l[p][ks], acc[p][nt], 0, 0, 0);
        acc[p][nt] = __builtin_amdgcn_mfma_f32_16x16x32_bf16(bl_, a_h[p][ks], acc[p][nt], 0, 0, 0);
      }
    }
  }
  float sg = 1.f / (1.f + expf(-skipp[0]));
  #pragma unroll
  for (int p = 0; p < 2; ++p){
    int r = (p0 + p)*16 + lr;
    if (r >= M) continue;
    #pragma unroll
    for (int nt = 0; nt < 8; ++nt){
      int c0 = nt*16 + lk*4;
      float4 bs  = *(const float4*)(bias + c0);
      float4 mx  = *(const float4*)(mixsrc + (size_t)r*128 + c0);
      float4 o4;
      o4.x = sg*(acc[p][nt][0] + bs.x) + (1.f - sg)*mx.x;
      o4.y = sg*(acc[p][nt][1] + bs.y) + (1.f - sg)*mx.y;
      o4.z = sg*(acc[p][nt][2] + bs.z) + (1.f - sg)*mx.z;
      o4.w = sg*(acc[p][nt][3] + bs.w) + (1.f - sg)*mx.w;
      *(float4*)(out + (size_t)r*128 + c0) = o4;
    }
  }
}

// ---------------- fused attention: 2 nodes per wave, unroll-4, bf16 Q ----------------
// Half-wave owns one node; L=lane&31 owns channels 4L..4L+3; head h=L>>3 (8-lane groups,
// 3-shfl reduce). One 16B gather per edge per lane (K-quad + V-quad). No max-shift.
__global__ __launch_bounds__(256)
void k_node(const unsigned short* __restrict__ KV, const unsigned short* __restrict__ Qb,
            const int* __restrict__ srcs, const int* __restrict__ row_ptr,
            const float* __restrict__ p,
            short* __restrict__ fh, short* __restrict__ fl, int NN){
  int wave = threadIdx.x >> 6;
  int lane = threadIdx.x & 63;
  int L = lane & 31;
  int node = blockIdx.x*8 + wave*2 + (lane >> 5);
  if (node >= NN) return;
  int start = row_ptr[node], end = row_ptr[node+1];
  int h = L >> 3;
  float ph = p[h] * 0.25504366769049834f;    // (1/sqrt(32))*log2(e)*p[h]
  const unsigned short* KVl = KV + L*8;
  uint2 qu = *(const uint2*)(Qb + (size_t)node*128 + L*4);
  float4 qv = make_float4(blo(qu.x), bhi(qu.x), blo(qu.y), bhi(qu.y));

  float a0=0.f, a1=0.f, a2=0.f, a3=0.f, den=0.f;
  int j = start;
  for (; j + 3 < end; j += 4){
    int s0 = srcs[j], s1 = srcs[j+1], s2 = srcs[j+2], s3 = srcs[j+3];
    uint4 kv0 = *(const uint4*)(KVl + (size_t)s0*256);
    uint4 kv1 = *(const uint4*)(KVl + (size_t)s1*256);
    uint4 kv2 = *(const uint4*)(KVl + (size_t)s2*256);
    uint4 kv3 = *(const uint4*)(KVl + (size_t)s3*256);
    float d0 = blo(kv0.x)*qv.x + bhi(kv0.x)*qv.y + blo(kv0.y)*qv.z + bhi(kv0.y)*qv.w;
    float d1 = blo(kv1.x)*qv.x + bhi(kv1.x)*qv.y + blo(kv1.y)*qv.z + bhi(kv1.y)*qv.w;
    float d2 = blo(kv2.x)*qv.x + bhi(kv2.x)*qv.y + blo(kv2.y)*qv.z + bhi(kv2.y)*qv.w;
    float d3 = blo(kv3.x)*qv.x + bhi(kv3.x)*qv.y + blo(kv3.y)*qv.z + bhi(kv3.y)*qv.w;
    #pragma unroll
    for (int m = 1; m < 8; m <<= 1){
      d0 += __shfl_xor(d0, m);
      d1 += __shfl_xor(d1, m);
      d2 += __shfl_xor(d2, m);
      d3 += __shfl_xor(d3, m);
    }
    float w0 = exp2f(d0 * ph);
    float w1 = exp2f(d1 * ph);
    float w2 = exp2f(d2 * ph);
    float w3 = exp2f(d3 * ph);
    den += (w0 + w1) + (w2 + w3);
    a0 += (w0*blo(kv0.z) + w1*blo(kv1.z)) + (w2*blo(kv2.z) + w3*blo(kv3.z));
    a1 += (w0*bhi(kv0.z) + w1*bhi(kv1.z)) + (w2*bhi(kv2.z) + w3*bhi(kv3.z));
    a2 += (w0*blo(kv0.w) + w1*blo(kv1.w)) + (w2*blo(kv2.w) + w3*blo(kv3.w));
    a3 += (w0*bhi(kv0.w) + w1*bhi(kv1.w)) + (w2*bhi(kv2.w) + w3*bhi(kv3.w));
  }
  for (; j < end; ++j){
    int s0 = srcs[j];
    uint4 kv0 = *(const uint4*)(KVl + (size_t)s0*256);
    float d0 = blo(kv0.x)*qv.x + bhi(kv0.x)*qv.y + blo(kv0.y)*qv.z + bhi(kv0.y)*qv.w;
    #pragma unroll
    for (int m = 1; m < 8; m <<= 1) d0 += __shfl_xor(d0, m);
    float w0 = exp2f(d0 * ph);
    den += w0;
    a0 += w0*blo(kv0.z);
    a1 += w0*bhi(kv0.z);
    a2 += w0*blo(kv0.w);
    a3 += w0*bhi(kv0.w);
  }
  float o[4] = {0.f, 0.f, 0.f, 0.f};
  if (end > start){
    float inv = 1.f / den;
    o[0] = gelu_exact(a0 * inv);
    o[1] = gelu_exact(a1 * inv);
    o[2] = gelu_exact(a2 * inv);
    o[3] = gelu_exact(a3 * inv);
  }
  // split hi/lo; 4 adjacent k-slots -> one 8B store per buffer (frag map = prep map)
  unsigned hh[4], ll[4];
  #pragma unroll
  for (int q = 0; q < 4; ++q){
    unsigned ub = __float_as_uint(o[q]);
    hh[q] = ub >> 16;
    ll[q] = __float_as_uint(o[q] - __uint_as_float(ub & 0xFFFF0000u)) >> 16;
  }
  size_t ci = (size_t)((node >> 4)*4 + h)*64 + (node & 15)*4 + ((L >> 1) & 3);
  size_t si = ci*8 + (L & 1)*4;
  uint2 uh = make_uint2(hh[0] | (hh[1] << 16), hh[2] | (hh[3] << 16));
  uint2 ul = make_uint2(ll[0] | (ll[1] << 16), ll[2] | (ll[3] << 16));
  *(uint2*)(fh + si) = uh;
  *(uint2*)(fl + si) = ul;
}

// ---------------- decoder ----------------
__global__ void k_gemv2(const float* __restrict__ z, const float* __restrict__ Wlp,
                        float* __restrict__ s1, float* __restrict__ s2, int NN){
  int n = blockIdx.x*256 + threadIdx.x;
  if (n >= NN) return;
  const float4* row = (const float4*)(z + (size_t)n*128);
  float a0 = 0.f, a1 = 0.f;
  #pragma unroll
  for (int i = 0; i < 32; ++i){
    float4 v  = row[i];
    float4 w1 = ((const float4*)Wlp)[i];
    float4 w2 = ((const float4*)Wlp)[32 + i];
    a0 += v.x*w1.x + v.y*w1.y + v.z*w1.z + v.w*w1.w;
    a1 += v.x*w2.x + v.y*w2.y + v.z*w2.z + v.w*w2.w;
  }
  s1[n] = a0; s2[n] = a1;
}

__global__ void k_decode(const int* __restrict__ pe, const int* __restrict__ ne,
                         const float* __restrict__ s1, const float* __restrict__ s2,
                         const float* __restrict__ blp, float* __restrict__ out, int P){
  int i = blockIdx.x*256 + threadIdx.x;
  if (i < P){
    out[i] = s1[pe[i]] + s2[pe[P + i]] + blp[0];
  } else if (i < 2*P){
    int j = i - P;
    out[P + j] = s1[ne[j]] + s2[ne[P + j]] + blp[0];
  }
}

extern "C" void kernel_launch(void* const* d_in, const int* in_sizes, int n_in,
                              void* d_out, int out_size, void* d_ws, size_t ws_size,
                              hipStream_t stream){
  const float* x      = (const float*)d_in[0];
  const int*   ei     = (const int*)d_in[1];
  const int*   pos_ei = (const int*)d_in[3];
  const int*   neg_ei = (const int*)d_in[4];
  const int NN = in_sizes[0] / 128;
  const int E  = in_sizes[1] / 2;
  const int P  = in_sizes[3] / 2;
  const int padM = CDIV(NN, 128) * 128;
  const int* e_src = ei;
  const int* e_dst = ei + E;

  char* wsb = (char*)d_ws;
  size_t off = 0;
  auto alloc = [&](size_t bytes)->char*{
    char* r = wsb + off;
    off = (off + bytes + 255) & ~(size_t)255;
    return r;
  };
  unsigned short* KV16 = (unsigned short*)alloc((size_t)NN*256*2);  // interleaved K/V quads
  unsigned short* Qb16 = (unsigned short*)alloc((size_t)NN*128*2);  // bf16 Q
  float* h1     = (float*)alloc((size_t)NN*128*4);
  float* h2     = (float*)alloc((size_t)NN*128*4);
  short* AfH    = (short*)alloc((size_t)padM*128*2);   // gelu(agg) frags from k_node
  short* AfL    = (short*)alloc((size_t)padM*128*2);
  int*   srcs   = (int*)alloc((size_t)E*4);
  int*   rowp   = (int*)alloc((size_t)(NN+1)*4);
  int*   deg    = (int*)alloc((size_t)NN*4);
  int*   cursor = (int*)alloc((size_t)NN*4);
  int*   partial= (int*)alloc(256*4);
  float* beffK  = (float*)alloc(128*4);
  float* beffV  = (float*)alloc(128*4);
  short* BfH    = (short*)alloc((size_t)4*16384*2);
  short* BfL    = (short*)alloc((size_t)4*16384*2);
  float* s1     = (float*)alloc((size_t)NN*4);
  float* s2     = (float*)alloc((size_t)NN*4);

  // ---- CSR (shared by both layers) ----
  const int nb = CDIV(NN, 256);     // 196 <= 256
  k_clear_int<<<CDIV(NN,256),256,0,stream>>>(deg, NN);
  k_deg<<<CDIV(E,256),256,0,stream>>>(e_dst, deg, E);
  k_scan_blk<<<nb,256,0,stream>>>(deg, rowp, partial, NN);
  k_scan_mid<<<1,256,0,stream>>>(partial, nb);
  k_scan_add<<<CDIV(NN,256),256,0,stream>>>(rowp, partial, cursor, NN, E);
  k_fill<<<CDIV(E,256),256,0,stream>>>(e_src, e_dst, cursor, srcs, E);

  const int gblk = padM / 128;
  auto layer = [&](const float* hin, float* hout, int base){
    const float* Wk  = (const float*)d_in[base+0];
    const float* bk  = (const float*)d_in[base+1];
    const float* Wq  = (const float*)d_in[base+2];
    const float* bq  = (const float*)d_in[base+3];
    const float* Wv  = (const float*)d_in[base+4];
    const float* bv  = (const float*)d_in[base+5];
    const float* a   = (const float*)d_in[base+6];
    const float* m   = (const float*)d_in[base+7];
    const float* p   = (const float*)d_in[base+8];
    const float* Wo  = (const float*)d_in[base+9];
    const float* bo  = (const float*)d_in[base+10];
    const float* sk  = (const float*)d_in[base+11];
    k_prep<<<CDIV(4*16384+256,256),256,0,stream>>>(Wk, bk, a, Wq, Wv, bv, m, Wo,
                                                   BfH, BfL, beffK, beffV);
    k_kqv<<<gblk,256,0,stream>>>(hin, BfH, beffK, bq, beffV, KV16, Qb16, NN);
    k_node<<<CDIV(NN,8),256,0,stream>>>(KV16, Qb16, srcs, rowp, p, AfH, AfL, NN);
    k_outgemm<<<gblk,256,0,stream>>>(AfH, AfL, BfH, BfL, bo, hin, sk, hout, NN);
  };
  layer(x,  h1, 5);
  layer(h1, h2, 17);

  k_gemv2<<<CDIV(NN,256),256,0,stream>>>(h2, (const float*)d_in[29], s1, s2, NN);
  k_decode<<<CDIV(2*P,256),256,0,stream>>>(pos_ei, neg_ei, s1, s2,
                                           (const float*)d_in[30], (float*)d_out, P);
}

// Round 17
// 328.101 us; speedup vs baseline: 2.0202x; 1.0237x over previous
//
#include <hip/hip_runtime.h>
#include <hip/hip_bf16.h>

#define CDIV(a,b) (((a)+(b)-1)/(b))

typedef __attribute__((ext_vector_type(8))) short bh8;     // 8 bf16 in 4 VGPRs
typedef __attribute__((ext_vector_type(4))) float f32x4;

__device__ __forceinline__ float gelu_exact(float x){
  return 0.5f * x * (1.0f + erff(x * 0.7071067811865475f));
}
__device__ __forceinline__ float blo(unsigned u){ return __uint_as_float(u << 16); }
__device__ __forceinline__ float bhi(unsigned u){ return __uint_as_float(u & 0xFFFF0000u); }
__device__ __forceinline__ unsigned short bf16bits(float x){
  __hip_bfloat16 b = __float2bfloat16(x);
  return *(unsigned short*)&b;
}

// ---------------- CSR build ----------------
__global__ void k_clear_int(int* __restrict__ p, int n){
  int i = blockIdx.x*256 + threadIdx.x;
  if (i < n) p[i] = 0;
}

__global__ void k_deg(const int* __restrict__ dst, int* __restrict__ deg, int E){
  int e = blockIdx.x*256 + threadIdx.x;
  if (e < E) atomicAdd(&deg[dst[e]], 1);
}

// ---- hierarchical scan: per-block exclusive scan + partials ----
__global__ void k_scan_blk(const int* __restrict__ deg, int* __restrict__ rowp,
                           int* __restrict__ partial, int N){
  __shared__ int buf[256];
  int i = blockIdx.x*256 + threadIdx.x;
  int v = (i < N) ? deg[i] : 0;
  buf[threadIdx.x] = v;
  __syncthreads();
  #pragma unroll
  for (int off = 1; off < 256; off <<= 1){
    int t = (threadIdx.x >= off) ? buf[threadIdx.x - off] : 0;
    __syncthreads();
    buf[threadIdx.x] += t;
    __syncthreads();
  }
  if (i < N) rowp[i] = buf[threadIdx.x] - v;        // exclusive within block
  if (threadIdx.x == 255) partial[blockIdx.x] = buf[255];
}

// single block: exclusive scan of partials (nb <= 256)
__global__ void k_scan_mid(int* __restrict__ partial, int nb){
  __shared__ int buf[256];
  int v = (threadIdx.x < nb) ? partial[threadIdx.x] : 0;
  buf[threadIdx.x] = v;
  __syncthreads();
  #pragma unroll
  for (int off = 1; off < 256; off <<= 1){
    int t = (threadIdx.x >= off) ? buf[threadIdx.x - off] : 0;
    __syncthreads();
    buf[threadIdx.x] += t;
    __syncthreads();
  }
  if (threadIdx.x < nb) partial[threadIdx.x] = buf[threadIdx.x] - v;  // exclusive
}

// adds block offsets; also emits cursor copy
__global__ void k_scan_add(int* __restrict__ rowp, const int* __restrict__ partial,
                           int* __restrict__ cursor, int N, int E){
  int i = blockIdx.x*256 + threadIdx.x;
  if (i < N){
    int v = rowp[i] + partial[i >> 8];
    rowp[i] = v;
    cursor[i] = v;
  }
  if (i == 0) rowp[N] = E;
}

__global__ void k_fill(const int* __restrict__ src, const int* __restrict__ dst,
                       int* __restrict__ cursor, int* __restrict__ srcs, int E){
  int e = blockIdx.x*256 + threadIdx.x;
  if (e >= E) return;
  int d = dst[e];
  int pos = atomicAdd(&cursor[d], 1);
  srcs[pos] = src[e];
}

// -------- fused weight prep: rel-fold + transpose + RNE bf16 into MFMA frag order --------
// groups: 0=K (fused Ak), 1=Q, 2=V (fused Av), 3=O. Also computes beffK/beffV.
// 2-term math everywhere -> only the hi (RNE-rounded) weight matters; no lo plane.
__global__ void k_prep(const float* __restrict__ Wk, const float* __restrict__ bk,
                       const float* __restrict__ Ak, const float* __restrict__ Wq,
                       const float* __restrict__ Wv, const float* __restrict__ bv,
                       const float* __restrict__ Av, const float* __restrict__ Wo,
                       short* __restrict__ BfH,
                       float* __restrict__ beffK, float* __restrict__ beffV){
  int t = blockIdx.x*256 + threadIdx.x;
  if (t < 4*16384){
    int g = t >> 14;
    int u = t & 16383;
    int k = u & 127, n = u >> 7;
    float x;
    if (g == 1)      x = Wq[(size_t)k*128 + n];
    else if (g == 3) x = Wo[(size_t)k*128 + n];
    else {
      const float* W = (g == 0) ? Wk : Wv;
      const float* A = (g == 0) ? Ak : Av;
      int h = n >> 5, e2 = n & 31;
      const float* s  = W + (size_t)k*128 + h*32;
      const float* Ah = A + h*1024 + e2;
      float acc = 0.f;
      #pragma unroll
      for (int d = 0; d < 32; ++d) acc += s[d] * Ah[d*32];
      x = acc;
    }
    int nt = n >> 4, lr = n & 15, ks = k >> 5, lk = (k >> 3) & 3, e = k & 7;
    size_t o = ((size_t)((g*8 + nt)*4 + ks)*64 + lr*4 + lk)*8 + e;
    BfH[o] = (short)bf16bits(x);          // RNE
  } else {
    int u = t - 4*16384;       // 0..255: effective biases
    if (u < 256){
      int which = u >> 7, n = u & 127;
      const float* b = which ? bv : bk;
      const float* A = which ? Av : Ak;
      int h = n >> 5, e2 = n & 31;
      const float* Ah = A + h*1024 + e2;
      float acc = 0.f;
      #pragma unroll
      for (int d = 0; d < 32; ++d) acc += b[h*32 + d] * Ah[d*32];
      (which ? beffV : beffK)[n] = acc;
    }
  }
}

// ---------------- fused K/Q/V GEMM, swapped operands, 2-term split ----------------
// acc = bh*ah + bh*al (weights RNE bf16, activations split fp32-accurate).
// Lane owns one node-row, 4 consecutive channels -> vectorized 8B stores.
__global__ __launch_bounds__(256)
void k_kqv(const float* __restrict__ A,
           const short* __restrict__ BfH,
           const float* __restrict__ bK, const float* __restrict__ bQ,
           const float* __restrict__ bV,
           unsigned short* __restrict__ KV16, unsigned short* __restrict__ Qb16, int M){
  const int tid = threadIdx.x;
  const int wm = tid >> 6, l = tid & 63;
  const int lr = l & 15, lk = l >> 4;
  const int perm = (lr*4 + lk)*8;
  const int p0 = blockIdx.x*8 + wm*2;

  bh8 a_h[2][4], a_l[2][4];
  #pragma unroll
  for (int p = 0; p < 2; ++p){
    int row = (p0 + p)*16 + lr;
    #pragma unroll
    for (int ks = 0; ks < 4; ++ks){
      float f[8] = {0.f,0.f,0.f,0.f,0.f,0.f,0.f,0.f};
      if (row < M){
        float4 va = *(const float4*)(A + (size_t)row*128 + ks*32 + lk*8);
        float4 vb = *(const float4*)(A + (size_t)row*128 + ks*32 + lk*8 + 4);
        f[0]=va.x; f[1]=va.y; f[2]=va.z; f[3]=va.w;
        f[4]=vb.x; f[5]=vb.y; f[6]=vb.z; f[7]=vb.w;
      }
      bh8 h8, l8;
      #pragma unroll
      for (int q = 0; q < 8; ++q){
        unsigned ub = __float_as_uint(f[q]);
        h8[q] = (short)(ub >> 16);
        float fhv = __uint_as_float(ub & 0xFFFF0000u);
        l8[q] = (short)(__float_as_uint(f[q] - fhv) >> 16);
      }
      a_h[p][ks] = h8;
      a_l[p][ks] = l8;
    }
  }

  #pragma unroll
  for (int g = 0; g < 3; ++g){
    f32x4 acc[2][8];
    #pragma unroll
    for (int p = 0; p < 2; ++p)
      #pragma unroll
      for (int i = 0; i < 8; ++i) acc[p][i] = (f32x4){0.f,0.f,0.f,0.f};
    #pragma unroll
    for (int ks = 0; ks < 4; ++ks){
      #pragma unroll
      for (int nt = 0; nt < 8; ++nt){
        size_t o = (size_t)((g*8 + nt)*4 + ks)*512 + perm;
        bh8 bh_ = *(const bh8*)(BfH + o);
        #pragma unroll
        for (int p = 0; p < 2; ++p){
          acc[p][nt] = __builtin_amdgcn_mfma_f32_16x16x32_bf16(bh_, a_h[p][ks], acc[p][nt], 0, 0, 0);
          acc[p][nt] = __builtin_amdgcn_mfma_f32_16x16x32_bf16(bh_, a_l[p][ks], acc[p][nt], 0, 0, 0);
        }
      }
    }
    const float* bias = (g==0) ? bK : (g==1) ? bQ : bV;
    #pragma unroll
    for (int p = 0; p < 2; ++p){
      int r = (p0 + p)*16 + lr;
      if (r >= M) continue;
      #pragma unroll
      for (int nt = 0; nt < 8; ++nt){
        int c0 = nt*16 + lk*4;
        float4 bs = *(const float4*)(bias + c0);
        float v0 = acc[p][nt][0] + bs.x;
        float v1 = acc[p][nt][1] + bs.y;
        float v2 = acc[p][nt][2] + bs.z;
        float v3 = acc[p][nt][3] + bs.w;
        unsigned u0 = (unsigned)bf16bits(v0) | ((unsigned)bf16bits(v1) << 16);
        unsigned u1 = (unsigned)bf16bits(v2) | ((unsigned)bf16bits(v3) << 16);
        if (g == 1){
          *(uint2*)(Qb16 + (size_t)r*128 + c0) = make_uint2(u0, u1);
        } else {
          *(uint2*)(KV16 + (size_t)r*256 + (size_t)(nt*4 + lk)*8 + ((g == 2) ? 4 : 0))
              = make_uint2(u0, u1);
        }
      }
    }
  }
}

// ---------------- out GEMM (swapped, 2-term): h = sg*(gelu(agg)@Wo + bo) + (1-sg)*hin ----------------
__global__ __launch_bounds__(256)
void k_outgemm(const short* __restrict__ AfH, const short* __restrict__ AfL,
               const short* __restrict__ BfH,
               const float* __restrict__ bias, const float* __restrict__ mixsrc,
               const float* __restrict__ skipp, float* __restrict__ out, int M){
  const int tid = threadIdx.x;
  const int wm = tid >> 6, l = tid & 63;
  const int lr = l & 15, lk = l >> 4;
  const int perm = (lr*4 + lk)*8;
  const int p0 = blockIdx.x*8 + wm*2;

  bh8 a_h[2][4], a_l[2][4];
  #pragma unroll
  for (int p = 0; p < 2; ++p)
    #pragma unroll
    for (int ks = 0; ks < 4; ++ks){
      size_t o = (size_t)((p0 + p)*4 + ks)*512 + perm;
      a_h[p][ks] = *(const bh8*)(AfH + o);
      a_l[p][ks] = *(const bh8*)(AfL + o);
    }

  f32x4 acc[2][8];
  #pragma unroll
  for (int p = 0; p < 2; ++p)
    #pragma unroll
    for (int i = 0; i < 8; ++i) acc[p][i] = (f32x4){0.f,0.f,0.f,0.f};
  #pragma unroll
  for (int ks = 0; ks < 4; ++ks){
    #pragma unroll
    for (int nt = 0; nt < 8; ++nt){
      size_t o = (size_t)((3*8 + nt)*4 + ks)*512 + perm;
      bh8 bh_ = *(const bh8*)(BfH + o);
      #pragma unroll
      for (int p = 0; p < 2; ++p){
        acc[p][nt] = __builtin_amdgcn_mfma_f32_16x16x32_bf16(bh_, a_h[p][ks], acc[p][nt], 0, 0, 0);
        acc[p][nt] = __builtin_amdgcn_mfma_f32_16x16x32_bf16(bh_, a_l[p][ks], acc[p][nt], 0, 0, 0);
      }
    }
  }
  float sg = 1.f / (1.f + expf(-skipp[0]));
  #pragma unroll
  for (int p = 0; p < 2; ++p){
    int r = (p0 + p)*16 + lr;
    if (r >= M) continue;
    #pragma unroll
    for (int nt = 0; nt < 8; ++nt){
      int c0 = nt*16 + lk*4;
      float4 bs  = *(const float4*)(bias + c0);
      float4 mx  = *(const float4*)(mixsrc + (size_t)r*128 + c0);
      float4 o4;
      o4.x = sg*(acc[p][nt][0] + bs.x) + (1.f - sg)*mx.x;
      o4.y = sg*(acc[p][nt][1] + bs.y) + (1.f - sg)*mx.y;
      o4.z = sg*(acc[p][nt][2] + bs.z) + (1.f - sg)*mx.z;
      o4.w = sg*(acc[p][nt][3] + bs.w) + (1.f - sg)*mx.w;
      *(float4*)(out + (size_t)r*128 + c0) = o4;
    }
  }
}

// ---------------- fused attention: 2 nodes per wave, unroll-4, bf16 Q ----------------
// Half-wave owns one node; L=lane&31 owns channels 4L..4L+3; head h=L>>3 (8-lane groups,
// 3-shfl reduce). One 16B gather per edge per lane (K-quad + V-quad). No max-shift.
__global__ __launch_bounds__(256)
void k_node(const unsigned short* __restrict__ KV, const unsigned short* __restrict__ Qb,
            const int* __restrict__ srcs, const int* __restrict__ row_ptr,
            const float* __restrict__ p,
            short* __restrict__ fh, short* __restrict__ fl, int NN){
  int wave = threadIdx.x >> 6;
  int lane = threadIdx.x & 63;
  int L = lane & 31;
  int node = blockIdx.x*8 + wave*2 + (lane >> 5);
  if (node >= NN) return;
  int start = row_ptr[node], end = row_ptr[node+1];
  int h = L >> 3;
  float ph = p[h] * 0.25504366769049834f;    // (1/sqrt(32))*log2(e)*p[h]
  const unsigned short* KVl = KV + L*8;
  uint2 qu = *(const uint2*)(Qb + (size_t)node*128 + L*4);
  float4 qv = make_float4(blo(qu.x), bhi(qu.x), blo(qu.y), bhi(qu.y));

  float a0=0.f, a1=0.f, a2=0.f, a3=0.f, den=0.f;
  int j = start;
  for (; j + 3 < end; j += 4){
    int s0 = srcs[j], s1 = srcs[j+1], s2 = srcs[j+2], s3 = srcs[j+3];
    uint4 kv0 = *(const uint4*)(KVl + (size_t)s0*256);
    uint4 kv1 = *(const uint4*)(KVl + (size_t)s1*256);
    uint4 kv2 = *(const uint4*)(KVl + (size_t)s2*256);
    uint4 kv3 = *(const uint4*)(KVl + (size_t)s3*256);
    float d0 = blo(kv0.x)*qv.x + bhi(kv0.x)*qv.y + blo(kv0.y)*qv.z + bhi(kv0.y)*qv.w;
    float d1 = blo(kv1.x)*qv.x + bhi(kv1.x)*qv.y + blo(kv1.y)*qv.z + bhi(kv1.y)*qv.w;
    float d2 = blo(kv2.x)*qv.x + bhi(kv2.x)*qv.y + blo(kv2.y)*qv.z + bhi(kv2.y)*qv.w;
    float d3 = blo(kv3.x)*qv.x + bhi(kv3.x)*qv.y + blo(kv3.y)*qv.z + bhi(kv3.y)*qv.w;
    #pragma unroll
    for (int m = 1; m < 8; m <<= 1){
      d0 += __shfl_xor(d0, m);
      d1 += __shfl_xor(d1, m);
      d2 += __shfl_xor(d2, m);
      d3 += __shfl_xor(d3, m);
    }
    float w0 = exp2f(d0 * ph);
    float w1 = exp2f(d1 * ph);
    float w2 = exp2f(d2 * ph);
    float w3 = exp2f(d3 * ph);
    den += (w0 + w1) + (w2 + w3);
    a0 += (w0*blo(kv0.z) + w1*blo(kv1.z)) + (w2*blo(kv2.z) + w3*blo(kv3.z));
    a1 += (w0*bhi(kv0.z) + w1*bhi(kv1.z)) + (w2*bhi(kv2.z) + w3*bhi(kv3.z));
    a2 += (w0*blo(kv0.w) + w1*blo(kv1.w)) + (w2*blo(kv2.w) + w3*blo(kv3.w));
    a3 += (w0*bhi(kv0.w) + w1*bhi(kv1.w)) + (w2*bhi(kv2.w) + w3*bhi(kv3.w));
  }
  for (; j < end; ++j){
    int s0 = srcs[j];
    uint4 kv0 = *(const uint4*)(KVl + (size_t)s0*256);
    float d0 = blo(kv0.x)*qv.x + bhi(kv0.x)*qv.y + blo(kv0.y)*qv.z + bhi(kv0.y)*qv.w;
    #pragma unroll
    for (int m = 1; m < 8; m <<= 1) d0 += __shfl_xor(d0, m);
    float w0 = exp2f(d0 * ph);
    den += w0;
    a0 += w0*blo(kv0.z);
    a1 += w0*bhi(kv0.z);
    a2 += w0*blo(kv0.w);
    a3 += w0*bhi(kv0.w);
  }
  float o[4] = {0.f, 0.f, 0.f, 0.f};
  if (end > start){
    float inv = 1.f / den;
    o[0] = gelu_exact(a0 * inv);
    o[1] = gelu_exact(a1 * inv);
    o[2] = gelu_exact(a2 * inv);
    o[3] = gelu_exact(a3 * inv);
  }
  // split hi/lo; 4 adjacent k-slots -> one 8B store per buffer (frag map = prep map)
  unsigned hh[4], ll[4];
  #pragma unroll
  for (int q = 0; q < 4; ++q){
    unsigned ub = __float_as_uint(o[q]);
    hh[q] = ub >> 16;
    ll[q] = __float_as_uint(o[q] - __uint_as_float(ub & 0xFFFF0000u)) >> 16;
  }
  size_t ci = (size_t)((node >> 4)*4 + h)*64 + (node & 15)*4 + ((L >> 1) & 3);
  size_t si = ci*8 + (L & 1)*4;
  uint2 uh = make_uint2(hh[0] | (hh[1] << 16), hh[2] | (hh[3] << 16));
  uint2 ul = make_uint2(ll[0] | (ll[1] << 16), ll[2] | (ll[3] << 16));
  *(uint2*)(fh + si) = uh;
  *(uint2*)(fl + si) = ul;
}

// ---------------- decoder ----------------
__global__ void k_gemv2(const float* __restrict__ z, const float* __restrict__ Wlp,
                        float* __restrict__ s1, float* __restrict__ s2, int NN){
  int n = blockIdx.x*256 + threadIdx.x;
  if (n >= NN) return;
  const float4* row = (const float4*)(z + (size_t)n*128);
  float a0 = 0.f, a1 = 0.f;
  #pragma unroll
  for (int i = 0; i < 32; ++i){
    float4 v  = row[i];
    float4 w1 = ((const float4*)Wlp)[i];
    float4 w2 = ((const float4*)Wlp)[32 + i];
    a0 += v.x*w1.x + v.y*w1.y + v.z*w1.z + v.w*w1.w;
    a1 += v.x*w2.x + v.y*w2.y + v.z*w2.z + v.w*w2.w;
  }
  s1[n] = a0; s2[n] = a1;
}

__global__ void k_decode(const int* __restrict__ pe, const int* __restrict__ ne,
                         const float* __restrict__ s1, const float* __restrict__ s2,
                         const float* __restrict__ blp, float* __restrict__ out, int P){
  int i = blockIdx.x*256 + threadIdx.x;
  if (i < P){
    out[i] = s1[pe[i]] + s2[pe[P + i]] + blp[0];
  } else if (i < 2*P){
    int j = i - P;
    out[P + j] = s1[ne[j]] + s2[ne[P + j]] + blp[0];
  }
}

extern "C" void kernel_launch(void* const* d_in, const int* in_sizes, int n_in,
                              void* d_out, int out_size, void* d_ws, size_t ws_size,
                              hipStream_t stream){
  const float* x      = (const float*)d_in[0];
  const int*   ei     = (const int*)d_in[1];
  const int*   pos_ei = (const int*)d_in[3];
  const int*   neg_ei = (const int*)d_in[4];
  const int NN = in_sizes[0] / 128;
  const int E  = in_sizes[1] / 2;
  const int P  = in_sizes[3] / 2;
  const int padM = CDIV(NN, 128) * 128;
  const int* e_src = ei;
  const int* e_dst = ei + E;

  char* wsb = (char*)d_ws;
  size_t off = 0;
  auto alloc = [&](size_t bytes)->char*{
    char* r = wsb + off;
    off = (off + bytes + 255) & ~(size_t)255;
    return r;
  };
  unsigned short* KV16 = (unsigned short*)alloc((size_t)NN*256*2);  // interleaved K/V quads
  unsigned short* Qb16 = (unsigned short*)alloc((size_t)NN*128*2);  // bf16 Q
  float* h1     = (float*)alloc((size_t)NN*128*4);
  float* h2     = (float*)alloc((size_t)NN*128*4);
  short* AfH    = (short*)alloc((size_t)padM*128*2);   // gelu(agg) frags from k_node
  short* AfL    = (short*)alloc((size_t)padM*128*2);
  int*   srcs   = (int*)alloc((size_t)E*4);
  int*   rowp   = (int*)alloc((size_t)(NN+1)*4);
  int*   deg    = (int*)alloc((size_t)NN*4);
  int*   cursor = (int*)alloc((size_t)NN*4);
  int*   partial= (int*)alloc(256*4);
  float* beffK1 = (float*)alloc(128*4);
  float* beffV1 = (float*)alloc(128*4);
  float* beffK2 = (float*)alloc(128*4);
  float* beffV2 = (float*)alloc(128*4);
  short* BfH1   = (short*)alloc((size_t)4*16384*2);
  short* BfH2   = (short*)alloc((size_t)4*16384*2);
  float* s1     = (float*)alloc((size_t)NN*4);
  float* s2     = (float*)alloc((size_t)NN*4);

  // ---- CSR (shared by both layers) + both layers' weight prep up-front ----
  const int nb = CDIV(NN, 256);     // 196 <= 256
  k_clear_int<<<CDIV(NN,256),256,0,stream>>>(deg, NN);
  k_deg<<<CDIV(E,256),256,0,stream>>>(e_dst, deg, E);
  k_scan_blk<<<nb,256,0,stream>>>(deg, rowp, partial, NN);
  k_scan_mid<<<1,256,0,stream>>>(partial, nb);
  k_scan_add<<<CDIV(NN,256),256,0,stream>>>(rowp, partial, cursor, NN, E);
  k_fill<<<CDIV(E,256),256,0,stream>>>(e_src, e_dst, cursor, srcs, E);
  k_prep<<<CDIV(4*16384+256,256),256,0,stream>>>(
      (const float*)d_in[5],  (const float*)d_in[6],  (const float*)d_in[11],
      (const float*)d_in[7],  (const float*)d_in[9],  (const float*)d_in[10],
      (const float*)d_in[12], (const float*)d_in[14],
      BfH1, beffK1, beffV1);
  k_prep<<<CDIV(4*16384+256,256),256,0,stream>>>(
      (const float*)d_in[17], (const float*)d_in[18], (const float*)d_in[23],
      (const float*)d_in[19], (const float*)d_in[21], (const float*)d_in[22],
      (const float*)d_in[24], (const float*)d_in[26],
      BfH2, beffK2, beffV2);

  const int gblk = padM / 128;
  auto layer = [&](const float* hin, float* hout, int base,
                   const short* BfH, const float* beffK, const float* beffV){
    const float* bq  = (const float*)d_in[base+3];
    const float* p   = (const float*)d_in[base+8];
    const float* bo  = (const float*)d_in[base+10];
    const float* sk  = (const float*)d_in[base+11];
    k_kqv<<<gblk,256,0,stream>>>(hin, BfH, beffK, bq, beffV, KV16, Qb16, NN);
    k_node<<<CDIV(NN,8),256,0,stream>>>(KV16, Qb16, srcs, rowp, p, AfH, AfL, NN);
    k_outgemm<<<gblk,256,0,stream>>>(AfH, AfL, BfH, bo, hin, sk, hout, NN);
  };
  layer(x,  h1, 5,  BfH1, beffK1, beffV1);
  layer(h1, h2, 17, BfH2, beffK2, beffV2);

  k_gemv2<<<CDIV(NN,256),256,0,stream>>>(h2, (const float*)d_in[29], s1, s2, NN);
  k_decode<<<CDIV(2*P,256),256,0,stream>>>(pos_ei, neg_ei, s1, s2,
                                           (const float*)d_in[30], (float*)d_out, P);
}

// Round 18
// 306.880 us; speedup vs baseline: 2.1599x; 1.0692x over previous
//
#include <hip/hip_runtime.h>
#include <hip/hip_bf16.h>

#define CDIV(a,b) (((a)+(b)-1)/(b))

typedef __attribute__((ext_vector_type(8))) short bh8;     // 8 bf16 in 4 VGPRs
typedef __attribute__((ext_vector_type(4))) float f32x4;

__device__ __forceinline__ float gelu_exact(float x){
  return 0.5f * x * (1.0f + erff(x * 0.7071067811865475f));
}
__device__ __forceinline__ float blo(unsigned u){ return __uint_as_float(u << 16); }
__device__ __forceinline__ float bhi(unsigned u){ return __uint_as_float(u & 0xFFFF0000u); }
__device__ __forceinline__ unsigned short bf16bits(float x){
  __hip_bfloat16 b = __float2bfloat16(x);
  return *(unsigned short*)&b;
}

// ---------------- CSR build ----------------
__global__ void k_clear_int(int* __restrict__ p, int n){
  int i = blockIdx.x*256 + threadIdx.x;
  if (i < n) p[i] = 0;
}

__global__ void k_deg(const int* __restrict__ dst, int* __restrict__ deg, int E){
  int e = blockIdx.x*256 + threadIdx.x;
  if (e < E) atomicAdd(&deg[dst[e]], 1);
}

// per-block exclusive scan + block totals
__global__ void k_scan_blk(const int* __restrict__ deg, int* __restrict__ rowp,
                           int* __restrict__ partial, int N){
  __shared__ int buf[256];
  int i = blockIdx.x*256 + threadIdx.x;
  int v = (i < N) ? deg[i] : 0;
  buf[threadIdx.x] = v;
  __syncthreads();
  #pragma unroll
  for (int off = 1; off < 256; off <<= 1){
    int t = (threadIdx.x >= off) ? buf[threadIdx.x - off] : 0;
    __syncthreads();
    buf[threadIdx.x] += t;
    __syncthreads();
  }
  if (i < N) rowp[i] = buf[threadIdx.x] - v;        // exclusive within block
  if (threadIdx.x == 255) partial[blockIdx.x] = buf[255];
}

// finalize: each block inline-reduces partial[0..bid-1], adds, emits cursor copy
__global__ void k_scan_fin(int* __restrict__ rowp, const int* __restrict__ partial,
                           int* __restrict__ cursor, int N, int E, int nb){
  __shared__ int ws[4];
  int t = threadIdx.x;
  int v = (t < nb && t < blockIdx.x) ? partial[t] : 0;
  #pragma unroll
  for (int m = 32; m; m >>= 1) v += __shfl_xor(v, m);
  if ((t & 63) == 0) ws[t >> 6] = v;
  __syncthreads();
  int pre = ws[0] + ws[1] + ws[2] + ws[3];
  int i = blockIdx.x*256 + t;
  if (i < N){
    int nv = rowp[i] + pre;
    rowp[i] = nv;
    cursor[i] = nv;
  }
  if (i == 0) rowp[N] = E;
}

__global__ void k_fill(const int* __restrict__ src, const int* __restrict__ dst,
                       int* __restrict__ cursor, int* __restrict__ srcs, int E){
  int e = blockIdx.x*256 + threadIdx.x;
  if (e >= E) return;
  int d = dst[e];
  int pos = atomicAdd(&cursor[d], 1);
  srcs[pos] = src[e];
}

// -------- fused weight prep: rel-fold + transpose + RNE bf16 into MFMA frag order --------
__global__ void k_prep(const float* __restrict__ Wk, const float* __restrict__ bk,
                       const float* __restrict__ Ak, const float* __restrict__ Wq,
                       const float* __restrict__ Wv, const float* __restrict__ bv,
                       const float* __restrict__ Av, const float* __restrict__ Wo,
                       short* __restrict__ BfH,
                       float* __restrict__ beffK, float* __restrict__ beffV){
  int t = blockIdx.x*256 + threadIdx.x;
  if (t < 4*16384){
    int g = t >> 14;
    int u = t & 16383;
    int k = u & 127, n = u >> 7;
    float x;
    if (g == 1)      x = Wq[(size_t)k*128 + n];
    else if (g == 3) x = Wo[(size_t)k*128 + n];
    else {
      const float* W = (g == 0) ? Wk : Wv;
      const float* A = (g == 0) ? Ak : Av;
      int h = n >> 5, e2 = n & 31;
      const float* s  = W + (size_t)k*128 + h*32;
      const float* Ah = A + h*1024 + e2;
      float acc = 0.f;
      #pragma unroll
      for (int d = 0; d < 32; ++d) acc += s[d] * Ah[d*32];
      x = acc;
    }
    int nt = n >> 4, lr = n & 15, ks = k >> 5, lk = (k >> 3) & 3, e = k & 7;
    size_t o = ((size_t)((g*8 + nt)*4 + ks)*64 + lr*4 + lk)*8 + e;
    BfH[o] = (short)bf16bits(x);          // RNE
  } else {
    int u = t - 4*16384;       // 0..255: effective biases
    if (u < 256){
      int which = u >> 7, n = u & 127;
      const float* b = which ? bv : bk;
      const float* A = which ? Av : Ak;
      int h = n >> 5, e2 = n & 31;
      const float* Ah = A + h*1024 + e2;
      float acc = 0.f;
      #pragma unroll
      for (int d = 0; d < 32; ++d) acc += b[h*32 + d] * Ah[d*32];
      (which ? beffV : beffK)[n] = acc;
    }
  }
}

// ---------------- fused K/Q/V GEMM, swapped operands, 2-term split ----------------
__global__ __launch_bounds__(256)
void k_kqv(const float* __restrict__ A,
           const short* __restrict__ BfH,
           const float* __restrict__ bK, const float* __restrict__ bQ,
           const float* __restrict__ bV,
           unsigned short* __restrict__ KV16, unsigned short* __restrict__ Qb16, int M){
  const int tid = threadIdx.x;
  const int wm = tid >> 6, l = tid & 63;
  const int lr = l & 15, lk = l >> 4;
  const int perm = (lr*4 + lk)*8;
  const int p0 = blockIdx.x*8 + wm*2;

  bh8 a_h[2][4], a_l[2][4];
  #pragma unroll
  for (int p = 0; p < 2; ++p){
    int row = (p0 + p)*16 + lr;
    #pragma unroll
    for (int ks = 0; ks < 4; ++ks){
      float f[8] = {0.f,0.f,0.f,0.f,0.f,0.f,0.f,0.f};
      if (row < M){
        float4 va = *(const float4*)(A + (size_t)row*128 + ks*32 + lk*8);
        float4 vb = *(const float4*)(A + (size_t)row*128 + ks*32 + lk*8 + 4);
        f[0]=va.x; f[1]=va.y; f[2]=va.z; f[3]=va.w;
        f[4]=vb.x; f[5]=vb.y; f[6]=vb.z; f[7]=vb.w;
      }
      bh8 h8, l8;
      #pragma unroll
      for (int q = 0; q < 8; ++q){
        unsigned ub = __float_as_uint(f[q]);
        h8[q] = (short)(ub >> 16);
        float fhv = __uint_as_float(ub & 0xFFFF0000u);
        l8[q] = (short)(__float_as_uint(f[q] - fhv) >> 16);
      }
      a_h[p][ks] = h8;
      a_l[p][ks] = l8;
    }
  }

  #pragma unroll
  for (int g = 0; g < 3; ++g){
    f32x4 acc[2][8];
    #pragma unroll
    for (int p = 0; p < 2; ++p)
      #pragma unroll
      for (int i = 0; i < 8; ++i) acc[p][i] = (f32x4){0.f,0.f,0.f,0.f};
    #pragma unroll
    for (int ks = 0; ks < 4; ++ks){
      #pragma unroll
      for (int nt = 0; nt < 8; ++nt){
        size_t o = (size_t)((g*8 + nt)*4 + ks)*512 + perm;
        bh8 bh_ = *(const bh8*)(BfH + o);
        #pragma unroll
        for (int p = 0; p < 2; ++p){
          acc[p][nt] = __builtin_amdgcn_mfma_f32_16x16x32_bf16(bh_, a_h[p][ks], acc[p][nt], 0, 0, 0);
          acc[p][nt] = __builtin_amdgcn_mfma_f32_16x16x32_bf16(bh_, a_l[p][ks], acc[p][nt], 0, 0, 0);
        }
      }
    }
    const float* bias = (g==0) ? bK : (g==1) ? bQ : bV;
    #pragma unroll
    for (int p = 0; p < 2; ++p){
      int r = (p0 + p)*16 + lr;
      if (r >= M) continue;
      #pragma unroll
      for (int nt = 0; nt < 8; ++nt){
        int c0 = nt*16 + lk*4;
        float4 bs = *(const float4*)(bias + c0);
        float v0 = acc[p][nt][0] + bs.x;
        float v1 = acc[p][nt][1] + bs.y;
        float v2 = acc[p][nt][2] + bs.z;
        float v3 = acc[p][nt][3] + bs.w;
        unsigned u0 = (unsigned)bf16bits(v0) | ((unsigned)bf16bits(v1) << 16);
        unsigned u1 = (unsigned)bf16bits(v2) | ((unsigned)bf16bits(v3) << 16);
        if (g == 1){
          *(uint2*)(Qb16 + (size_t)r*128 + c0) = make_uint2(u0, u1);
        } else {
          *(uint2*)(KV16 + (size_t)r*256 + (size_t)(nt*4 + lk)*8 + ((g == 2) ? 4 : 0))
              = make_uint2(u0, u1);
        }
      }
    }
  }
}

// ---------------- out GEMM (swapped, 1-term, bf16 activations) ----------------
// DECODE=true (layer 2): h2 never stored; per-row Wlp dots computed in-kernel.
template<bool DECODE>
__global__ __launch_bounds__(256)
void k_outgemm(const short* __restrict__ AfH,
               const short* __restrict__ BfH,
               const float* __restrict__ bias, const float* __restrict__ mixsrc,
               const float* __restrict__ skipp, float* __restrict__ out,
               const float* __restrict__ Wlp,
               float* __restrict__ s1, float* __restrict__ s2, int M){
  const int tid = threadIdx.x;
  const int wm = tid >> 6, l = tid & 63;
  const int lr = l & 15, lk = l >> 4;
  const int perm = (lr*4 + lk)*8;
  const int p0 = blockIdx.x*8 + wm*2;

  bh8 a_h[2][4];
  #pragma unroll
  for (int p = 0; p < 2; ++p)
    #pragma unroll
    for (int ks = 0; ks < 4; ++ks){
      size_t o = (size_t)((p0 + p)*4 + ks)*512 + perm;
      a_h[p][ks] = *(const bh8*)(AfH + o);
    }

  f32x4 acc[2][8];
  #pragma unroll
  for (int p = 0; p < 2; ++p)
    #pragma unroll
    for (int i = 0; i < 8; ++i) acc[p][i] = (f32x4){0.f,0.f,0.f,0.f};
  #pragma unroll
  for (int ks = 0; ks < 4; ++ks){
    #pragma unroll
    for (int nt = 0; nt < 8; ++nt){
      size_t o = (size_t)((3*8 + nt)*4 + ks)*512 + perm;
      bh8 bh_ = *(const bh8*)(BfH + o);
      #pragma unroll
      for (int p = 0; p < 2; ++p){
        acc[p][nt] = __builtin_amdgcn_mfma_f32_16x16x32_bf16(bh_, a_h[p][ks], acc[p][nt], 0, 0, 0);
      }
    }
  }
  float sg = 1.f / (1.f + expf(-skipp[0]));
  #pragma unroll
  for (int p = 0; p < 2; ++p){
    int r = (p0 + p)*16 + lr;
    if (r >= M) continue;
    float d1 = 0.f, d2 = 0.f;
    #pragma unroll
    for (int nt = 0; nt < 8; ++nt){
      int c0 = nt*16 + lk*4;
      float4 bs  = *(const float4*)(bias + c0);
      float4 mx  = *(const float4*)(mixsrc + (size_t)r*128 + c0);
      float4 o4;
      o4.x = sg*(acc[p][nt][0] + bs.x) + (1.f - sg)*mx.x;
      o4.y = sg*(acc[p][nt][1] + bs.y) + (1.f - sg)*mx.y;
      o4.z = sg*(acc[p][nt][2] + bs.z) + (1.f - sg)*mx.z;
      o4.w = sg*(acc[p][nt][3] + bs.w) + (1.f - sg)*mx.w;
      if (DECODE){
        float4 w1 = *(const float4*)(Wlp + c0);
        float4 w2 = *(const float4*)(Wlp + 128 + c0);
        d1 += o4.x*w1.x + o4.y*w1.y + o4.z*w1.z + o4.w*w1.w;
        d2 += o4.x*w2.x + o4.y*w2.y + o4.z*w2.z + o4.w*w2.w;
      } else {
        *(float4*)(out + (size_t)r*128 + c0) = o4;
      }
    }
    if (DECODE){
      d1 += __shfl_xor(d1, 16); d1 += __shfl_xor(d1, 32);
      d2 += __shfl_xor(d2, 16); d2 += __shfl_xor(d2, 32);
      if (lk == 0){ s1[r] = d1; s2[r] = d2; }
    }
  }
}

// ---------------- fused attention: 2 nodes per wave, unroll-4, bf16 Q ----------------
// Epilogue now stores RNE bf16 (hi plane only) in MFMA fragment order.
__global__ __launch_bounds__(256)
void k_node(const unsigned short* __restrict__ KV, const unsigned short* __restrict__ Qb,
            const int* __restrict__ srcs, const int* __restrict__ row_ptr,
            const float* __restrict__ p,
            short* __restrict__ fh, int NN){
  int wave = threadIdx.x >> 6;
  int lane = threadIdx.x & 63;
  int L = lane & 31;
  int node = blockIdx.x*8 + wave*2 + (lane >> 5);
  if (node >= NN) return;
  int start = row_ptr[node], end = row_ptr[node+1];
  int h = L >> 3;
  float ph = p[h] * 0.25504366769049834f;    // (1/sqrt(32))*log2(e)*p[h]
  const unsigned short* KVl = KV + L*8;
  uint2 qu = *(const uint2*)(Qb + (size_t)node*128 + L*4);
  float4 qv = make_float4(blo(qu.x), bhi(qu.x), blo(qu.y), bhi(qu.y));

  float a0=0.f, a1=0.f, a2=0.f, a3=0.f, den=0.f;
  int j = start;
  for (; j + 3 < end; j += 4){
    int s0 = srcs[j], s1 = srcs[j+1], s2 = srcs[j+2], s3 = srcs[j+3];
    uint4 kv0 = *(const uint4*)(KVl + (size_t)s0*256);
    uint4 kv1 = *(const uint4*)(KVl + (size_t)s1*256);
    uint4 kv2 = *(const uint4*)(KVl + (size_t)s2*256);
    uint4 kv3 = *(const uint4*)(KVl + (size_t)s3*256);
    float d0 = blo(kv0.x)*qv.x + bhi(kv0.x)*qv.y + blo(kv0.y)*qv.z + bhi(kv0.y)*qv.w;
    float d1 = blo(kv1.x)*qv.x + bhi(kv1.x)*qv.y + blo(kv1.y)*qv.z + bhi(kv1.y)*qv.w;
    float d2 = blo(kv2.x)*qv.x + bhi(kv2.x)*qv.y + blo(kv2.y)*qv.z + bhi(kv2.y)*qv.w;
    float d3 = blo(kv3.x)*qv.x + bhi(kv3.x)*qv.y + blo(kv3.y)*qv.z + bhi(kv3.y)*qv.w;
    #pragma unroll
    for (int m = 1; m < 8; m <<= 1){
      d0 += __shfl_xor(d0, m);
      d1 += __shfl_xor(d1, m);
      d2 += __shfl_xor(d2, m);
      d3 += __shfl_xor(d3, m);
    }
    float w0 = exp2f(d0 * ph);
    float w1 = exp2f(d1 * ph);
    float w2 = exp2f(d2 * ph);
    float w3 = exp2f(d3 * ph);
    den += (w0 + w1) + (w2 + w3);
    a0 += (w0*blo(kv0.z) + w1*blo(kv1.z)) + (w2*blo(kv2.z) + w3*blo(kv3.z));
    a1 += (w0*bhi(kv0.z) + w1*bhi(kv1.z)) + (w2*bhi(kv2.z) + w3*bhi(kv3.z));
    a2 += (w0*blo(kv0.w) + w1*blo(kv1.w)) + (w2*blo(kv2.w) + w3*blo(kv3.w));
    a3 += (w0*bhi(kv0.w) + w1*bhi(kv1.w)) + (w2*bhi(kv2.w) + w3*bhi(kv3.w));
  }
  for (; j < end; ++j){
    int s0 = srcs[j];
    uint4 kv0 = *(const uint4*)(KVl + (size_t)s0*256);
    float d0 = blo(kv0.x)*qv.x + bhi(kv0.x)*qv.y + blo(kv0.y)*qv.z + bhi(kv0.y)*qv.w;
    #pragma unroll
    for (int m = 1; m < 8; m <<= 1) d0 += __shfl_xor(d0, m);
    float w0 = exp2f(d0 * ph);
    den += w0;
    a0 += w0*blo(kv0.z);
    a1 += w0*bhi(kv0.z);
    a2 += w0*blo(kv0.w);
    a3 += w0*bhi(kv0.w);
  }
  float o[4] = {0.f, 0.f, 0.f, 0.f};
  if (end > start){
    float inv = 1.f / den;
    o[0] = gelu_exact(a0 * inv);
    o[1] = gelu_exact(a1 * inv);
    o[2] = gelu_exact(a2 * inv);
    o[3] = gelu_exact(a3 * inv);
  }
  size_t ci = (size_t)((node >> 4)*4 + h)*64 + (node & 15)*4 + ((L >> 1) & 3);
  size_t si = ci*8 + (L & 1)*4;
  uint2 uh = make_uint2((unsigned)bf16bits(o[0]) | ((unsigned)bf16bits(o[1]) << 16),
                        (unsigned)bf16bits(o[2]) | ((unsigned)bf16bits(o[3]) << 16));
  *(uint2*)(fh + si) = uh;
}

__global__ void k_decode(const int* __restrict__ pe, const int* __restrict__ ne,
                         const float* __restrict__ s1, const float* __restrict__ s2,
                         const float* __restrict__ blp, float* __restrict__ out, int P){
  int i = blockIdx.x*256 + threadIdx.x;
  if (i < P){
    out[i] = s1[pe[i]] + s2[pe[P + i]] + blp[0];
  } else if (i < 2*P){
    int j = i - P;
    out[P + j] = s1[ne[j]] + s2[ne[P + j]] + blp[0];
  }
}

extern "C" void kernel_launch(void* const* d_in, const int* in_sizes, int n_in,
                              void* d_out, int out_size, void* d_ws, size_t ws_size,
                              hipStream_t stream){
  const float* x      = (const float*)d_in[0];
  const int*   ei     = (const int*)d_in[1];
  const int*   pos_ei = (const int*)d_in[3];
  const int*   neg_ei = (const int*)d_in[4];
  const int NN = in_sizes[0] / 128;
  const int E  = in_sizes[1] / 2;
  const int P  = in_sizes[3] / 2;
  const int padM = CDIV(NN, 128) * 128;
  const int* e_src = ei;
  const int* e_dst = ei + E;

  char* wsb = (char*)d_ws;
  size_t off = 0;
  auto alloc = [&](size_t bytes)->char*{
    char* r = wsb + off;
    off = (off + bytes + 255) & ~(size_t)255;
    return r;
  };
  unsigned short* KV16 = (unsigned short*)alloc((size_t)NN*256*2);  // interleaved K/V quads
  unsigned short* Qb16 = (unsigned short*)alloc((size_t)NN*128*2);  // bf16 Q
  float* h1     = (float*)alloc((size_t)NN*128*4);
  short* AfH    = (short*)alloc((size_t)padM*128*2);   // gelu(agg) frags from k_node
  int*   srcs   = (int*)alloc((size_t)E*4);
  int*   rowp   = (int*)alloc((size_t)(NN+1)*4);
  int*   deg    = (int*)alloc((size_t)NN*4);
  int*   cursor = (int*)alloc((size_t)NN*4);
  int*   partial= (int*)alloc(256*4);
  float* beffK1 = (float*)alloc(128*4);
  float* beffV1 = (float*)alloc(128*4);
  float* beffK2 = (float*)alloc(128*4);
  float* beffV2 = (float*)alloc(128*4);
  short* BfH1   = (short*)alloc((size_t)4*16384*2);
  short* BfH2   = (short*)alloc((size_t)4*16384*2);
  float* s1     = (float*)alloc((size_t)NN*4);
  float* s2     = (float*)alloc((size_t)NN*4);

  // ---- CSR (shared) + both layers' weight prep up-front ----
  const int nb = CDIV(NN, 256);     // 196 <= 256
  k_clear_int<<<CDIV(NN,256),256,0,stream>>>(deg, NN);
  k_deg<<<CDIV(E,256),256,0,stream>>>(e_dst, deg, E);
  k_scan_blk<<<nb,256,0,stream>>>(deg, rowp, partial, NN);
  k_scan_fin<<<nb,256,0,stream>>>(rowp, partial, cursor, NN, E, nb);
  k_fill<<<CDIV(E,256),256,0,stream>>>(e_src, e_dst, cursor, srcs, E);
  k_prep<<<CDIV(4*16384+256,256),256,0,stream>>>(
      (const float*)d_in[5],  (const float*)d_in[6],  (const float*)d_in[11],
      (const float*)d_in[7],  (const float*)d_in[9],  (const float*)d_in[10],
      (const float*)d_in[12], (const float*)d_in[14],
      BfH1, beffK1, beffV1);
  k_prep<<<CDIV(4*16384+256,256),256,0,stream>>>(
      (const float*)d_in[17], (const float*)d_in[18], (const float*)d_in[23],
      (const float*)d_in[19], (const float*)d_in[21], (const float*)d_in[22],
      (const float*)d_in[24], (const float*)d_in[26],
      BfH2, beffK2, beffV2);

  const int gblk = padM / 128;
  const float* Wlp = (const float*)d_in[29];

  // ---- layer 1 ----
  k_kqv<<<gblk,256,0,stream>>>(x, BfH1, beffK1, (const float*)d_in[8], beffV1,
                               KV16, Qb16, NN);
  k_node<<<CDIV(NN,8),256,0,stream>>>(KV16, Qb16, srcs, rowp,
                                      (const float*)d_in[13], AfH, NN);
  k_outgemm<false><<<gblk,256,0,stream>>>(AfH, BfH1, (const float*)d_in[15], x,
                                          (const float*)d_in[16], h1,
                                          nullptr, nullptr, nullptr, NN);
  // ---- layer 2 (decode fused; h2 never materialized) ----
  k_kqv<<<gblk,256,0,stream>>>(h1, BfH2, beffK2, (const float*)d_in[20], beffV2,
                               KV16, Qb16, NN);
  k_node<<<CDIV(NN,8),256,0,stream>>>(KV16, Qb16, srcs, rowp,
                                      (const float*)d_in[25], AfH, NN);
  k_outgemm<true><<<gblk,256,0,stream>>>(AfH, BfH2, (const float*)d_in[27], h1,
                                         (const float*)d_in[28], nullptr,
                                         Wlp, s1, s2, NN);

  k_decode<<<CDIV(2*P,256),256,0,stream>>>(pos_ei, neg_ei, s1, s2,
                                           (const float*)d_in[30], (float*)d_out, P);
}

// Round 19
// 305.174 us; speedup vs baseline: 2.1719x; 1.0056x over previous
//
#include <hip/hip_runtime.h>
#include <hip/hip_bf16.h>

#define CDIV(a,b) (((a)+(b)-1)/(b))

typedef __attribute__((ext_vector_type(8))) short bh8;     // 8 bf16 in 4 VGPRs
typedef __attribute__((ext_vector_type(4))) float f32x4;

__device__ __forceinline__ float gelu_exact(float x){
  return 0.5f * x * (1.0f + erff(x * 0.7071067811865475f));
}
__device__ __forceinline__ float blo(unsigned u){ return __uint_as_float(u << 16); }
__device__ __forceinline__ float bhi(unsigned u){ return __uint_as_float(u & 0xFFFF0000u); }
__device__ __forceinline__ unsigned short bf16bits(float x){
  __hip_bfloat16 b = __float2bfloat16(x);
  return *(unsigned short*)&b;
}

// ---------------- CSR build ----------------
__global__ void k_clear_int(int* __restrict__ p, int n){
  int i = blockIdx.x*256 + threadIdx.x;
  if (i < n) p[i] = 0;
}

__global__ void k_deg(const int* __restrict__ dst, int* __restrict__ deg, int E){
  int e = blockIdx.x*256 + threadIdx.x;
  if (e < E) atomicAdd(&deg[dst[e]], 1);
}

// per-block exclusive scan + block totals
__global__ void k_scan_blk(const int* __restrict__ deg, int* __restrict__ rowp,
                           int* __restrict__ partial, int N){
  __shared__ int buf[256];
  int i = blockIdx.x*256 + threadIdx.x;
  int v = (i < N) ? deg[i] : 0;
  buf[threadIdx.x] = v;
  __syncthreads();
  #pragma unroll
  for (int off = 1; off < 256; off <<= 1){
    int t = (threadIdx.x >= off) ? buf[threadIdx.x - off] : 0;
    __syncthreads();
    buf[threadIdx.x] += t;
    __syncthreads();
  }
  if (i < N) rowp[i] = buf[threadIdx.x] - v;        // exclusive within block
  if (threadIdx.x == 255) partial[blockIdx.x] = buf[255];
}

// finalize: each block inline-reduces partial[0..bid-1], adds, emits cursor copy
__global__ void k_scan_fin(int* __restrict__ rowp, const int* __restrict__ partial,
                           int* __restrict__ cursor, int N, int E, int nb){
  __shared__ int ws[4];
  int t = threadIdx.x;
  int v = (t < nb && t < blockIdx.x) ? partial[t] : 0;
  #pragma unroll
  for (int m = 32; m; m >>= 1) v += __shfl_xor(v, m);
  if ((t & 63) == 0) ws[t >> 6] = v;
  __syncthreads();
  int pre = ws[0] + ws[1] + ws[2] + ws[3];
  int i = blockIdx.x*256 + t;
  if (i < N){
    int nv = rowp[i] + pre;
    rowp[i] = nv;
    cursor[i] = nv;
  }
  if (i == 0) rowp[N] = E;
}

__global__ void k_fill(const int* __restrict__ src, const int* __restrict__ dst,
                       int* __restrict__ cursor, int* __restrict__ srcs, int E){
  int e = blockIdx.x*256 + threadIdx.x;
  if (e >= E) return;
  int d = dst[e];
  int pos = atomicAdd(&cursor[d], 1);
  srcs[pos] = src[e];
}

// -------- both layers' weight prep in one launch: rel-fold + RNE bf16 frag order --------
__device__ __forceinline__ void prep_one(int u,
    const float* Wk, const float* bk, const float* Ak, const float* Wq,
    const float* Wv, const float* bv, const float* Av, const float* Wo,
    short* BfH, float* beffK, float* beffV){
  if (u < 4*16384){
    int g = u >> 14;
    int w = u & 16383;
    int k = w & 127, n = w >> 7;
    float x;
    if (g == 1)      x = Wq[(size_t)k*128 + n];
    else if (g == 3) x = Wo[(size_t)k*128 + n];
    else {
      const float* W = (g == 0) ? Wk : Wv;
      const float* A = (g == 0) ? Ak : Av;
      int h = n >> 5, e2 = n & 31;
      const float* s  = W + (size_t)k*128 + h*32;
      const float* Ah = A + h*1024 + e2;
      float acc = 0.f;
      #pragma unroll
      for (int d = 0; d < 32; ++d) acc += s[d] * Ah[d*32];
      x = acc;
    }
    int nt = n >> 4, lr = n & 15, ks = k >> 5, lk = (k >> 3) & 3, e = k & 7;
    size_t o = ((size_t)((g*8 + nt)*4 + ks)*64 + lr*4 + lk)*8 + e;
    BfH[o] = (short)bf16bits(x);          // RNE
  } else {
    int w = u - 4*16384;
    if (w < 256){
      int which = w >> 7, n = w & 127;
      const float* b = which ? bv : bk;
      const float* A = which ? Av : Ak;
      int h = n >> 5, e2 = n & 31;
      const float* Ah = A + h*1024 + e2;
      float acc = 0.f;
      #pragma unroll
      for (int d = 0; d < 32; ++d) acc += b[h*32 + d] * Ah[d*32];
      (which ? beffV : beffK)[n] = acc;
    }
  }
}

__global__ void k_prep2(
    const float* Wk1, const float* bk1, const float* Ak1, const float* Wq1,
    const float* Wv1, const float* bv1, const float* Av1, const float* Wo1,
    const float* Wk2, const float* bk2, const float* Ak2, const float* Wq2,
    const float* Wv2, const float* bv2, const float* Av2, const float* Wo2,
    short* __restrict__ BfH1, short* __restrict__ BfH2,
    float* __restrict__ beffK1, float* __restrict__ beffV1,
    float* __restrict__ beffK2, float* __restrict__ beffV2){
  const int SZ = 4*16384 + 256;
  int t = blockIdx.x*256 + threadIdx.x;
  if (t < SZ)
    prep_one(t, Wk1, bk1, Ak1, Wq1, Wv1, bv1, Av1, Wo1, BfH1, beffK1, beffV1);
  else if (t < 2*SZ)
    prep_one(t - SZ, Wk2, bk2, Ak2, Wq2, Wv2, bv2, Av2, Wo2, BfH2, beffK2, beffV2);
}

// ---------------- fused K/Q/V GEMM, swapped operands, 1-term (bf16 x bf16) ----------------
// BF16IN: A is row-major bf16 -> fragments load directly, zero conversion.
template<bool BF16IN>
__global__ __launch_bounds__(256)
void k_kqv(const void* __restrict__ Ain,
           const short* __restrict__ BfH,
           const float* __restrict__ bK, const float* __restrict__ bQ,
           const float* __restrict__ bV,
           unsigned short* __restrict__ KV16, unsigned short* __restrict__ Qb16, int M){
  const int tid = threadIdx.x;
  const int wm = tid >> 6, l = tid & 63;
  const int lr = l & 15, lk = l >> 4;
  const int perm = (lr*4 + lk)*8;
  const int p0 = blockIdx.x*8 + wm*2;

  bh8 a_h[2][4];
  #pragma unroll
  for (int p = 0; p < 2; ++p){
    int row = (p0 + p)*16 + lr;
    #pragma unroll
    for (int ks = 0; ks < 4; ++ks){
      if (BF16IN){
        bh8 z = (bh8){0,0,0,0,0,0,0,0};
        if (row < M)
          z = *(const bh8*)((const short*)Ain + (size_t)row*128 + ks*32 + lk*8);
        a_h[p][ks] = z;
      } else {
        const float* A = (const float*)Ain;
        float f[8] = {0.f,0.f,0.f,0.f,0.f,0.f,0.f,0.f};
        if (row < M){
          float4 va = *(const float4*)(A + (size_t)row*128 + ks*32 + lk*8);
          float4 vb = *(const float4*)(A + (size_t)row*128 + ks*32 + lk*8 + 4);
          f[0]=va.x; f[1]=va.y; f[2]=va.z; f[3]=va.w;
          f[4]=vb.x; f[5]=vb.y; f[6]=vb.z; f[7]=vb.w;
        }
        bh8 h8;
        #pragma unroll
        for (int q = 0; q < 8; ++q) h8[q] = (short)bf16bits(f[q]);   // RNE
        a_h[p][ks] = h8;
      }
    }
  }

  #pragma unroll
  for (int g = 0; g < 3; ++g){
    f32x4 acc[2][8];
    #pragma unroll
    for (int p = 0; p < 2; ++p)
      #pragma unroll
      for (int i = 0; i < 8; ++i) acc[p][i] = (f32x4){0.f,0.f,0.f,0.f};
    #pragma unroll
    for (int ks = 0; ks < 4; ++ks){
      #pragma unroll
      for (int nt = 0; nt < 8; ++nt){
        size_t o = (size_t)((g*8 + nt)*4 + ks)*512 + perm;
        bh8 bh_ = *(const bh8*)(BfH + o);
        #pragma unroll
        for (int p = 0; p < 2; ++p){
          acc[p][nt] = __builtin_amdgcn_mfma_f32_16x16x32_bf16(bh_, a_h[p][ks], acc[p][nt], 0, 0, 0);
        }
      }
    }
    const float* bias = (g==0) ? bK : (g==1) ? bQ : bV;
    #pragma unroll
    for (int p = 0; p < 2; ++p){
      int r = (p0 + p)*16 + lr;
      if (r >= M) continue;
      #pragma unroll
      for (int nt = 0; nt < 8; ++nt){
        int c0 = nt*16 + lk*4;
        float4 bs = *(const float4*)(bias + c0);
        float v0 = acc[p][nt][0] + bs.x;
        float v1 = acc[p][nt][1] + bs.y;
        float v2 = acc[p][nt][2] + bs.z;
        float v3 = acc[p][nt][3] + bs.w;
        unsigned u0 = (unsigned)bf16bits(v0) | ((unsigned)bf16bits(v1) << 16);
        unsigned u1 = (unsigned)bf16bits(v2) | ((unsigned)bf16bits(v3) << 16);
        if (g == 1){
          *(uint2*)(Qb16 + (size_t)r*128 + c0) = make_uint2(u0, u1);
        } else {
          *(uint2*)(KV16 + (size_t)r*256 + (size_t)(nt*4 + lk)*8 + ((g == 2) ? 4 : 0))
              = make_uint2(u0, u1);
        }
      }
    }
  }
}

// ---------------- out GEMM (swapped, 1-term, bf16 activations) ----------------
// DECODE=false: writes h1 as packed bf16 (h1b). DECODE=true: fused Wlp decode, no h2.
// MIXBF16: mixsrc is packed bf16 (h1b) instead of fp32.
template<bool DECODE, bool MIXBF16>
__global__ __launch_bounds__(256)
void k_outgemm(const short* __restrict__ AfH,
               const short* __restrict__ BfH,
               const float* __restrict__ bias, const void* __restrict__ mixsrc,
               const float* __restrict__ skipp, unsigned short* __restrict__ outb,
               const float* __restrict__ Wlp,
               float* __restrict__ s1, float* __restrict__ s2, int M){
  const int tid = threadIdx.x;
  const int wm = tid >> 6, l = tid & 63;
  const int lr = l & 15, lk = l >> 4;
  const int perm = (lr*4 + lk)*8;
  const int p0 = blockIdx.x*8 + wm*2;

  bh8 a_h[2][4];
  #pragma unroll
  for (int p = 0; p < 2; ++p)
    #pragma unroll
    for (int ks = 0; ks < 4; ++ks){
      size_t o = (size_t)((p0 + p)*4 + ks)*512 + perm;
      a_h[p][ks] = *(const bh8*)(AfH + o);
    }

  f32x4 acc[2][8];
  #pragma unroll
  for (int p = 0; p < 2; ++p)
    #pragma unroll
    for (int i = 0; i < 8; ++i) acc[p][i] = (f32x4){0.f,0.f,0.f,0.f};
  #pragma unroll
  for (int ks = 0; ks < 4; ++ks){
    #pragma unroll
    for (int nt = 0; nt < 8; ++nt){
      size_t o = (size_t)((3*8 + nt)*4 + ks)*512 + perm;
      bh8 bh_ = *(const bh8*)(BfH + o);
      #pragma unroll
      for (int p = 0; p < 2; ++p){
        acc[p][nt] = __builtin_amdgcn_mfma_f32_16x16x32_bf16(bh_, a_h[p][ks], acc[p][nt], 0, 0, 0);
      }
    }
  }
  float sg = 1.f / (1.f + expf(-skipp[0]));
  #pragma unroll
  for (int p = 0; p < 2; ++p){
    int r = (p0 + p)*16 + lr;
    if (r >= M) continue;
    float d1 = 0.f, d2 = 0.f;
    #pragma unroll
    for (int nt = 0; nt < 8; ++nt){
      int c0 = nt*16 + lk*4;
      float4 bs = *(const float4*)(bias + c0);
      float4 mx;
      if (MIXBF16){
        uint2 mu = *(const uint2*)((const unsigned short*)mixsrc + (size_t)r*128 + c0);
        mx = make_float4(blo(mu.x), bhi(mu.x), blo(mu.y), bhi(mu.y));
      } else {
        mx = *(const float4*)((const float*)mixsrc + (size_t)r*128 + c0);
      }
      float4 o4;
      o4.x = sg*(acc[p][nt][0] + bs.x) + (1.f - sg)*mx.x;
      o4.y = sg*(acc[p][nt][1] + bs.y) + (1.f - sg)*mx.y;
      o4.z = sg*(acc[p][nt][2] + bs.z) + (1.f - sg)*mx.z;
      o4.w = sg*(acc[p][nt][3] + bs.w) + (1.f - sg)*mx.w;
      if (DECODE){
        float4 w1 = *(const float4*)(Wlp + c0);
        float4 w2 = *(const float4*)(Wlp + 128 + c0);
        d1 += o4.x*w1.x + o4.y*w1.y + o4.z*w1.z + o4.w*w1.w;
        d2 += o4.x*w2.x + o4.y*w2.y + o4.z*w2.z + o4.w*w2.w;
      } else {
        unsigned u0 = (unsigned)bf16bits(o4.x) | ((unsigned)bf16bits(o4.y) << 16);
        unsigned u1 = (unsigned)bf16bits(o4.z) | ((unsigned)bf16bits(o4.w) << 16);
        *(uint2*)(outb + (size_t)r*128 + c0) = make_uint2(u0, u1);
      }
    }
    if (DECODE){
      d1 += __shfl_xor(d1, 16); d1 += __shfl_xor(d1, 32);
      d2 += __shfl_xor(d2, 16); d2 += __shfl_xor(d2, 32);
      if (lk == 0){ s1[r] = d1; s2[r] = d2; }
    }
  }
}

// ---------------- fused attention: 2 nodes per wave, unroll-4, bf16 Q ----------------
__global__ __launch_bounds__(256)
void k_node(const unsigned short* __restrict__ KV, const unsigned short* __restrict__ Qb,
            const int* __restrict__ srcs, const int* __restrict__ row_ptr,
            const float* __restrict__ p,
            short* __restrict__ fh, int NN){
  int wave = threadIdx.x >> 6;
  int lane = threadIdx.x & 63;
  int L = lane & 31;
  int node = blockIdx.x*8 + wave*2 + (lane >> 5);
  if (node >= NN) return;
  int start = row_ptr[node], end = row_ptr[node+1];
  int h = L >> 3;
  float ph = p[h] * 0.25504366769049834f;    // (1/sqrt(32))*log2(e)*p[h]
  const unsigned short* KVl = KV + L*8;
  uint2 qu = *(const uint2*)(Qb + (size_t)node*128 + L*4);
  float4 qv = make_float4(blo(qu.x), bhi(qu.x), blo(qu.y), bhi(qu.y));

  float a0=0.f, a1=0.f, a2=0.f, a3=0.f, den=0.f;
  int j = start;
  for (; j + 3 < end; j += 4){
    int s0 = srcs[j], s1 = srcs[j+1], s2 = srcs[j+2], s3 = srcs[j+3];
    uint4 kv0 = *(const uint4*)(KVl + (size_t)s0*256);
    uint4 kv1 = *(const uint4*)(KVl + (size_t)s1*256);
    uint4 kv2 = *(const uint4*)(KVl + (size_t)s2*256);
    uint4 kv3 = *(const uint4*)(KVl + (size_t)s3*256);
    float d0 = blo(kv0.x)*qv.x + bhi(kv0.x)*qv.y + blo(kv0.y)*qv.z + bhi(kv0.y)*qv.w;
    float d1 = blo(kv1.x)*qv.x + bhi(kv1.x)*qv.y + blo(kv1.y)*qv.z + bhi(kv1.y)*qv.w;
    float d2 = blo(kv2.x)*qv.x + bhi(kv2.x)*qv.y + blo(kv2.y)*qv.z + bhi(kv2.y)*qv.w;
    float d3 = blo(kv3.x)*qv.x + bhi(kv3.x)*qv.y + blo(kv3.y)*qv.z + bhi(kv3.y)*qv.w;
    #pragma unroll
    for (int m = 1; m < 8; m <<= 1){
      d0 += __shfl_xor(d0, m);
      d1 += __shfl_xor(d1, m);
      d2 += __shfl_xor(d2, m);
      d3 += __shfl_xor(d3, m);
    }
    float w0 = exp2f(d0 * ph);
    float w1 = exp2f(d1 * ph);
    float w2 = exp2f(d2 * ph);
    float w3 = exp2f(d3 * ph);
    den += (w0 + w1) + (w2 + w3);
    a0 += (w0*blo(kv0.z) + w1*blo(kv1.z)) + (w2*blo(kv2.z) + w3*blo(kv3.z));
    a1 += (w0*bhi(kv0.z) + w1*bhi(kv1.z)) + (w2*bhi(kv2.z) + w3*bhi(kv3.z));
    a2 += (w0*blo(kv0.w) + w1*blo(kv1.w)) + (w2*blo(kv2.w) + w3*blo(kv3.w));
    a3 += (w0*bhi(kv0.w) + w1*bhi(kv1.w)) + (w2*bhi(kv2.w) + w3*bhi(kv3.w));
  }
  for (; j < end; ++j){
    int s0 = srcs[j];
    uint4 kv0 = *(const uint4*)(KVl + (size_t)s0*256);
    float d0 = blo(kv0.x)*qv.x + bhi(kv0.x)*qv.y + blo(kv0.y)*qv.z + bhi(kv0.y)*qv.w;
    #pragma unroll
    for (int m = 1; m < 8; m <<= 1) d0 += __shfl_xor(d0, m);
    float w0 = exp2f(d0 * ph);
    den += w0;
    a0 += w0*blo(kv0.z);
    a1 += w0*bhi(kv0.z);
    a2 += w0*blo(kv0.w);
    a3 += w0*bhi(kv0.w);
  }
  float o[4] = {0.f, 0.f, 0.f, 0.f};
  if (end > start){
    float inv = 1.f / den;
    o[0] = gelu_exact(a0 * inv);
    o[1] = gelu_exact(a1 * inv);
    o[2] = gelu_exact(a2 * inv);
    o[3] = gelu_exact(a3 * inv);
  }
  size_t ci = (size_t)((node >> 4)*4 + h)*64 + (node & 15)*4 + ((L >> 1) & 3);
  size_t si = ci*8 + (L & 1)*4;
  uint2 uh = make_uint2((unsigned)bf16bits(o[0]) | ((unsigned)bf16bits(o[1]) << 16),
                        (unsigned)bf16bits(o[2]) | ((unsigned)bf16bits(o[3]) << 16));
  *(uint2*)(fh + si) = uh;
}

__global__ void k_decode(const int* __restrict__ pe, const int* __restrict__ ne,
                         const float* __restrict__ s1, const float* __restrict__ s2,
                         const float* __restrict__ blp, float* __restrict__ out, int P){
  int i = blockIdx.x*256 + threadIdx.x;
  if (i < P){
    out[i] = s1[pe[i]] + s2[pe[P + i]] + blp[0];
  } else if (i < 2*P){
    int j = i - P;
    out[P + j] = s1[ne[j]] + s2[ne[P + j]] + blp[0];
  }
}

extern "C" void kernel_launch(void* const* d_in, const int* in_sizes, int n_in,
                              void* d_out, int out_size, void* d_ws, size_t ws_size,
                              hipStream_t stream){
  const float* x      = (const float*)d_in[0];
  const int*   ei     = (const int*)d_in[1];
  const int*   pos_ei = (const int*)d_in[3];
  const int*   neg_ei = (const int*)d_in[4];
  const int NN = in_sizes[0] / 128;
  const int E  = in_sizes[1] / 2;
  const int P  = in_sizes[3] / 2;
  const int padM = CDIV(NN, 128) * 128;
  const int* e_src = ei;
  const int* e_dst = ei + E;

  char* wsb = (char*)d_ws;
  size_t off = 0;
  auto alloc = [&](size_t bytes)->char*{
    char* r = wsb + off;
    off = (off + bytes + 255) & ~(size_t)255;
    return r;
  };
  unsigned short* KV16 = (unsigned short*)alloc((size_t)NN*256*2);  // interleaved K/V quads
  unsigned short* Qb16 = (unsigned short*)alloc((size_t)NN*128*2);  // bf16 Q
  unsigned short* h1b  = (unsigned short*)alloc((size_t)NN*128*2);  // bf16 h1
  short* AfH    = (short*)alloc((size_t)padM*128*2);   // gelu(agg) frags from k_node
  int*   srcs   = (int*)alloc((size_t)E*4);
  int*   rowp   = (int*)alloc((size_t)(NN+1)*4);
  int*   deg    = (int*)alloc((size_t)NN*4);
  int*   cursor = (int*)alloc((size_t)NN*4);
  int*   partial= (int*)alloc(256*4);
  float* beffK1 = (float*)alloc(128*4);
  float* beffV1 = (float*)alloc(128*4);
  float* beffK2 = (float*)alloc(128*4);
  float* beffV2 = (float*)alloc(128*4);
  short* BfH1   = (short*)alloc((size_t)4*16384*2);
  short* BfH2   = (short*)alloc((size_t)4*16384*2);
  float* s1     = (float*)alloc((size_t)NN*4);
  float* s2     = (float*)alloc((size_t)NN*4);

  // ---- CSR (shared) + both layers' weight prep (one launch) ----
  const int nb = CDIV(NN, 256);     // 196 <= 256
  k_clear_int<<<CDIV(NN,256),256,0,stream>>>(deg, NN);
  k_deg<<<CDIV(E,256),256,0,stream>>>(e_dst, deg, E);
  k_scan_blk<<<nb,256,0,stream>>>(deg, rowp, partial, NN);
  k_scan_fin<<<nb,256,0,stream>>>(rowp, partial, cursor, NN, E, nb);
  k_fill<<<CDIV(E,256),256,0,stream>>>(e_src, e_dst, cursor, srcs, E);
  k_prep2<<<CDIV(2*(4*16384+256),256),256,0,stream>>>(
      (const float*)d_in[5],  (const float*)d_in[6],  (const float*)d_in[11],
      (const float*)d_in[7],  (const float*)d_in[9],  (const float*)d_in[10],
      (const float*)d_in[12], (const float*)d_in[14],
      (const float*)d_in[17], (const float*)d_in[18], (const float*)d_in[23],
      (const float*)d_in[19], (const float*)d_in[21], (const float*)d_in[22],
      (const float*)d_in[24], (const float*)d_in[26],
      BfH1, BfH2, beffK1, beffV1, beffK2, beffV2);

  const int gblk = padM / 128;
  const float* Wlp = (const float*)d_in[29];

  // ---- layer 1 (fp32 x in; h1 emitted as bf16) ----
  k_kqv<false><<<gblk,256,0,stream>>>(x, BfH1, beffK1, (const float*)d_in[8], beffV1,
                                      KV16, Qb16, NN);
  k_node<<<CDIV(NN,8),256,0,stream>>>(KV16, Qb16, srcs, rowp,
                                      (const float*)d_in[13], AfH, NN);
  k_outgemm<false,false><<<gblk,256,0,stream>>>(AfH, BfH1, (const float*)d_in[15], x,
                                                (const float*)d_in[16], h1b,
                                                nullptr, nullptr, nullptr, NN);
  // ---- layer 2 (bf16 h1 in; decode fused; h2 never materialized) ----
  k_kqv<true><<<gblk,256,0,stream>>>(h1b, BfH2, beffK2, (const float*)d_in[20], beffV2,
                                     KV16, Qb16, NN);
  k_node<<<CDIV(NN,8),256,0,stream>>>(KV16, Qb16, srcs, rowp,
                                      (const float*)d_in[25], AfH, NN);
  k_outgemm<true,true><<<gblk,256,0,stream>>>(AfH, BfH2, (const float*)d_in[27], h1b,
                                              (const float*)d_in[28], nullptr,
                                              Wlp, s1, s2, NN);

  k_decode<<<CDIV(2*P,256),256,0,stream>>>(pos_ei, neg_ei, s1, s2,
                                           (const float*)d_in[30], (float*)d_out, P);
}

// Round 20
// 301.265 us; speedup vs baseline: 2.2001x; 1.0130x over previous
//
#include <hip/hip_runtime.h>
#include <hip/hip_bf16.h>

#define CDIV(a,b) (((a)+(b)-1)/(b))

typedef __attribute__((ext_vector_type(8))) short bh8;     // 8 bf16 in 4 VGPRs
typedef __attribute__((ext_vector_type(4))) float f32x4;

__device__ __forceinline__ float gelu_exact(float x){
  return 0.5f * x * (1.0f + erff(x * 0.7071067811865475f));
}
__device__ __forceinline__ float blo(unsigned u){ return __uint_as_float(u << 16); }
__device__ __forceinline__ float bhi(unsigned u){ return __uint_as_float(u & 0xFFFF0000u); }
__device__ __forceinline__ unsigned short bf16bits(float x){
  __hip_bfloat16 b = __float2bfloat16(x);
  return *(unsigned short*)&b;
}

// ---------------- CSR build ----------------
__global__ void k_clear_int(int* __restrict__ p, int n){
  int i = blockIdx.x*256 + threadIdx.x;
  if (i < n) p[i] = 0;
}

__global__ void k_deg(const int* __restrict__ dst, int* __restrict__ deg, int E){
  int e = blockIdx.x*256 + threadIdx.x;
  if (e < E) atomicAdd(&deg[dst[e]], 1);
}

// per-block exclusive scan + block totals
__global__ void k_scan_blk(const int* __restrict__ deg, int* __restrict__ rowp,
                           int* __restrict__ partial, int N){
  __shared__ int buf[256];
  int i = blockIdx.x*256 + threadIdx.x;
  int v = (i < N) ? deg[i] : 0;
  buf[threadIdx.x] = v;
  __syncthreads();
  #pragma unroll
  for (int off = 1; off < 256; off <<= 1){
    int t = (threadIdx.x >= off) ? buf[threadIdx.x - off] : 0;
    __syncthreads();
    buf[threadIdx.x] += t;
    __syncthreads();
  }
  if (i < N) rowp[i] = buf[threadIdx.x] - v;        // exclusive within block
  if (threadIdx.x == 255) partial[blockIdx.x] = buf[255];
}

// finalize: each block inline-reduces partial[0..bid-1], adds, emits cursor copy
__global__ void k_scan_fin(int* __restrict__ rowp, const int* __restrict__ partial,
                           int* __restrict__ cursor, int N, int E, int nb){
  __shared__ int ws[4];
  int t = threadIdx.x;
  int v = (t < nb && t < blockIdx.x) ? partial[t] : 0;
  #pragma unroll
  for (int m = 32; m; m >>= 1) v += __shfl_xor(v, m);
  if ((t & 63) == 0) ws[t >> 6] = v;
  __syncthreads();
  int pre = ws[0] + ws[1] + ws[2] + ws[3];
  int i = blockIdx.x*256 + t;
  if (i < N){
    int nv = rowp[i] + pre;
    rowp[i] = nv;
    cursor[i] = nv;
  }
  if (i == 0) rowp[N] = E;
}

__global__ void k_fill(const int* __restrict__ src, const int* __restrict__ dst,
                       int* __restrict__ cursor, int* __restrict__ srcs, int E){
  int e = blockIdx.x*256 + threadIdx.x;
  if (e >= E) return;
  int d = dst[e];
  int pos = atomicAdd(&cursor[d], 1);
  srcs[pos] = src[e];
}

// -------- both layers' weight prep in one launch: rel-fold + RNE bf16 frag order --------
__device__ __forceinline__ void prep_one(int u,
    const float* Wk, const float* bk, const float* Ak, const float* Wq,
    const float* Wv, const float* bv, const float* Av, const float* Wo,
    short* BfH, float* beffK, float* beffV){
  if (u < 4*16384){
    int g = u >> 14;
    int w = u & 16383;
    int k = w & 127, n = w >> 7;
    float x;
    if (g == 1)      x = Wq[(size_t)k*128 + n];
    else if (g == 3) x = Wo[(size_t)k*128 + n];
    else {
      const float* W = (g == 0) ? Wk : Wv;
      const float* A = (g == 0) ? Ak : Av;
      int h = n >> 5, e2 = n & 31;
      const float* s  = W + (size_t)k*128 + h*32;
      const float* Ah = A + h*1024 + e2;
      float acc = 0.f;
      #pragma unroll
      for (int d = 0; d < 32; ++d) acc += s[d] * Ah[d*32];
      x = acc;
    }
    int nt = n >> 4, lr = n & 15, ks = k >> 5, lk = (k >> 3) & 3, e = k & 7;
    size_t o = ((size_t)((g*8 + nt)*4 + ks)*64 + lr*4 + lk)*8 + e;
    BfH[o] = (short)bf16bits(x);          // RNE
  } else {
    int w = u - 4*16384;
    if (w < 256){
      int which = w >> 7, n = w & 127;
      const float* b = which ? bv : bk;
      const float* A = which ? Av : Ak;
      int h = n >> 5, e2 = n & 31;
      const float* Ah = A + h*1024 + e2;
      float acc = 0.f;
      #pragma unroll
      for (int d = 0; d < 32; ++d) acc += b[h*32 + d] * Ah[d*32];
      (which ? beffV : beffK)[n] = acc;
    }
  }
}

__global__ void k_prep2(
    const float* Wk1, const float* bk1, const float* Ak1, const float* Wq1,
    const float* Wv1, const float* bv1, const float* Av1, const float* Wo1,
    const float* Wk2, const float* bk2, const float* Ak2, const float* Wq2,
    const float* Wv2, const float* bv2, const float* Av2, const float* Wo2,
    short* __restrict__ BfH1, short* __restrict__ BfH2,
    float* __restrict__ beffK1, float* __restrict__ beffV1,
    float* __restrict__ beffK2, float* __restrict__ beffV2){
  const int SZ = 4*16384 + 256;
  int t = blockIdx.x*256 + threadIdx.x;
  if (t < SZ)
    prep_one(t, Wk1, bk1, Ak1, Wq1, Wv1, bv1, Av1, Wo1, BfH1, beffK1, beffV1);
  else if (t < 2*SZ)
    prep_one(t - SZ, Wk2, bk2, Ak2, Wq2, Wv2, bv2, Av2, Wo2, BfH2, beffK2, beffV2);
}

// ---------------- fused K/Q/V GEMM: 64-thread blocks (1 wave, 2 panels = 32 rows) ----------------
// Swapped operands, 1-term bf16xbf16. BF16IN: A row-major bf16 -> direct frag loads.
template<bool BF16IN>
__global__ __launch_bounds__(64)
void k_kqv(const void* __restrict__ Ain,
           const short* __restrict__ BfH,
           const float* __restrict__ bK, const float* __restrict__ bQ,
           const float* __restrict__ bV,
           unsigned short* __restrict__ KV16, unsigned short* __restrict__ Qb16, int M){
  const int l = threadIdx.x;
  const int lr = l & 15, lk = l >> 4;
  const int perm = (lr*4 + lk)*8;
  const int p0 = blockIdx.x*2;

  bh8 a_h[2][4];
  #pragma unroll
  for (int p = 0; p < 2; ++p){
    int row = (p0 + p)*16 + lr;
    #pragma unroll
    for (int ks = 0; ks < 4; ++ks){
      if (BF16IN){
        bh8 z = (bh8){0,0,0,0,0,0,0,0};
        if (row < M)
          z = *(const bh8*)((const short*)Ain + (size_t)row*128 + ks*32 + lk*8);
        a_h[p][ks] = z;
      } else {
        const float* A = (const float*)Ain;
        float f[8] = {0.f,0.f,0.f,0.f,0.f,0.f,0.f,0.f};
        if (row < M){
          float4 va = *(const float4*)(A + (size_t)row*128 + ks*32 + lk*8);
          float4 vb = *(const float4*)(A + (size_t)row*128 + ks*32 + lk*8 + 4);
          f[0]=va.x; f[1]=va.y; f[2]=va.z; f[3]=va.w;
          f[4]=vb.x; f[5]=vb.y; f[6]=vb.z; f[7]=vb.w;
        }
        bh8 h8;
        #pragma unroll
        for (int q = 0; q < 8; ++q) h8[q] = (short)bf16bits(f[q]);   // RNE
        a_h[p][ks] = h8;
      }
    }
  }

  #pragma unroll
  for (int g = 0; g < 3; ++g){
    f32x4 acc[2][8];
    #pragma unroll
    for (int p = 0; p < 2; ++p)
      #pragma unroll
      for (int i = 0; i < 8; ++i) acc[p][i] = (f32x4){0.f,0.f,0.f,0.f};
    #pragma unroll
    for (int ks = 0; ks < 4; ++ks){
      #pragma unroll
      for (int nt = 0; nt < 8; ++nt){
        size_t o = (size_t)((g*8 + nt)*4 + ks)*512 + perm;
        bh8 bh_ = *(const bh8*)(BfH + o);
        #pragma unroll
        for (int p = 0; p < 2; ++p){
          acc[p][nt] = __builtin_amdgcn_mfma_f32_16x16x32_bf16(bh_, a_h[p][ks], acc[p][nt], 0, 0, 0);
        }
      }
    }
    const float* bias = (g==0) ? bK : (g==1) ? bQ : bV;
    #pragma unroll
    for (int p = 0; p < 2; ++p){
      int r = (p0 + p)*16 + lr;
      if (r >= M) continue;
      #pragma unroll
      for (int nt = 0; nt < 8; ++nt){
        int c0 = nt*16 + lk*4;
        float4 bs = *(const float4*)(bias + c0);
        float v0 = acc[p][nt][0] + bs.x;
        float v1 = acc[p][nt][1] + bs.y;
        float v2 = acc[p][nt][2] + bs.z;
        float v3 = acc[p][nt][3] + bs.w;
        unsigned u0 = (unsigned)bf16bits(v0) | ((unsigned)bf16bits(v1) << 16);
        unsigned u1 = (unsigned)bf16bits(v2) | ((unsigned)bf16bits(v3) << 16);
        if (g == 1){
          *(uint2*)(Qb16 + (size_t)r*128 + c0) = make_uint2(u0, u1);
        } else {
          *(uint2*)(KV16 + (size_t)r*256 + (size_t)(nt*4 + lk)*8 + ((g == 2) ? 4 : 0))
              = make_uint2(u0, u1);
        }
      }
    }
  }
}

// ---------------- out GEMM: 64-thread blocks, 1-term, bf16 activations ----------------
// DECODE=false: writes h1 packed bf16. DECODE=true: fused Wlp decode, no h2.
template<bool DECODE, bool MIXBF16>
__global__ __launch_bounds__(64)
void k_outgemm(const short* __restrict__ AfH,
               const short* __restrict__ BfH,
               const float* __restrict__ bias, const void* __restrict__ mixsrc,
               const float* __restrict__ skipp, unsigned short* __restrict__ outb,
               const float* __restrict__ Wlp,
               float* __restrict__ s1, float* __restrict__ s2, int M){
  const int l = threadIdx.x;
  const int lr = l & 15, lk = l >> 4;
  const int perm = (lr*4 + lk)*8;
  const int p0 = blockIdx.x*2;

  bh8 a_h[2][4];
  #pragma unroll
  for (int p = 0; p < 2; ++p)
    #pragma unroll
    for (int ks = 0; ks < 4; ++ks){
      size_t o = (size_t)((p0 + p)*4 + ks)*512 + perm;
      a_h[p][ks] = *(const bh8*)(AfH + o);
    }

  f32x4 acc[2][8];
  #pragma unroll
  for (int p = 0; p < 2; ++p)
    #pragma unroll
    for (int i = 0; i < 8; ++i) acc[p][i] = (f32x4){0.f,0.f,0.f,0.f};
  #pragma unroll
  for (int ks = 0; ks < 4; ++ks){
    #pragma unroll
    for (int nt = 0; nt < 8; ++nt){
      size_t o = (size_t)((3*8 + nt)*4 + ks)*512 + perm;
      bh8 bh_ = *(const bh8*)(BfH + o);
      #pragma unroll
      for (int p = 0; p < 2; ++p){
        acc[p][nt] = __builtin_amdgcn_mfma_f32_16x16x32_bf16(bh_, a_h[p][ks], acc[p][nt], 0, 0, 0);
      }
    }
  }
  float sg = 1.f / (1.f + expf(-skipp[0]));
  #pragma unroll
  for (int p = 0; p < 2; ++p){
    int r = (p0 + p)*16 + lr;
    if (r >= M) continue;
    float d1 = 0.f, d2 = 0.f;
    #pragma unroll
    for (int nt = 0; nt < 8; ++nt){
      int c0 = nt*16 + lk*4;
      float4 bs = *(const float4*)(bias + c0);
      float4 mx;
      if (MIXBF16){
        uint2 mu = *(const uint2*)((const unsigned short*)mixsrc + (size_t)r*128 + c0);
        mx = make_float4(blo(mu.x), bhi(mu.x), blo(mu.y), bhi(mu.y));
      } else {
        mx = *(const float4*)((const float*)mixsrc + (size_t)r*128 + c0);
      }
      float4 o4;
      o4.x = sg*(acc[p][nt][0] + bs.x) + (1.f - sg)*mx.x;
      o4.y = sg*(acc[p][nt][1] + bs.y) + (1.f - sg)*mx.y;
      o4.z = sg*(acc[p][nt][2] + bs.z) + (1.f - sg)*mx.z;
      o4.w = sg*(acc[p][nt][3] + bs.w) + (1.f - sg)*mx.w;
      if (DECODE){
        float4 w1 = *(const float4*)(Wlp + c0);
        float4 w2 = *(const float4*)(Wlp + 128 + c0);
        d1 += o4.x*w1.x + o4.y*w1.y + o4.z*w1.z + o4.w*w1.w;
        d2 += o4.x*w2.x + o4.y*w2.y + o4.z*w2.z + o4.w*w2.w;
      } else {
        unsigned u0 = (unsigned)bf16bits(o4.x) | ((unsigned)bf16bits(o4.y) << 16);
        unsigned u1 = (unsigned)bf16bits(o4.z) | ((unsigned)bf16bits(o4.w) << 16);
        *(uint2*)(outb + (size_t)r*128 + c0) = make_uint2(u0, u1);
      }
    }
    if (DECODE){
      d1 += __shfl_xor(d1, 16); d1 += __shfl_xor(d1, 32);
      d2 += __shfl_xor(d2, 16); d2 += __shfl_xor(d2, 32);
      if (lk == 0){ s1[r] = d1; s2[r] = d2; }
    }
  }
}

// ---------------- fused attention: 2 nodes per wave, unroll-4, bf16 Q ----------------
__global__ __launch_bounds__(256)
void k_node(const unsigned short* __restrict__ KV, const unsigned short* __restrict__ Qb,
            const int* __restrict__ srcs, const int* __restrict__ row_ptr,
            const float* __restrict__ p,
            short* __restrict__ fh, int NN){
  int wave = threadIdx.x >> 6;
  int lane = threadIdx.x & 63;
  int L = lane & 31;
  int node = blockIdx.x*8 + wave*2 + (lane >> 5);
  if (node >= NN) return;
  int start = row_ptr[node], end = row_ptr[node+1];
  int h = L >> 3;
  float ph = p[h] * 0.25504366769049834f;    // (1/sqrt(32))*log2(e)*p[h]
  const unsigned short* KVl = KV + L*8;
  uint2 qu = *(const uint2*)(Qb + (size_t)node*128 + L*4);
  float4 qv = make_float4(blo(qu.x), bhi(qu.x), blo(qu.y), bhi(qu.y));

  float a0=0.f, a1=0.f, a2=0.f, a3=0.f, den=0.f;
  int j = start;
  for (; j + 3 < end; j += 4){
    int s0 = srcs[j], s1 = srcs[j+1], s2 = srcs[j+2], s3 = srcs[j+3];
    uint4 kv0 = *(const uint4*)(KVl + (size_t)s0*256);
    uint4 kv1 = *(const uint4*)(KVl + (size_t)s1*256);
    uint4 kv2 = *(const uint4*)(KVl + (size_t)s2*256);
    uint4 kv3 = *(const uint4*)(KVl + (size_t)s3*256);
    float d0 = blo(kv0.x)*qv.x + bhi(kv0.x)*qv.y + blo(kv0.y)*qv.z + bhi(kv0.y)*qv.w;
    float d1 = blo(kv1.x)*qv.x + bhi(kv1.x)*qv.y + blo(kv1.y)*qv.z + bhi(kv1.y)*qv.w;
    float d2 = blo(kv2.x)*qv.x + bhi(kv2.x)*qv.y + blo(kv2.y)*qv.z + bhi(kv2.y)*qv.w;
    float d3 = blo(kv3.x)*qv.x + bhi(kv3.x)*qv.y + blo(kv3.y)*qv.z + bhi(kv3.y)*qv.w;
    #pragma unroll
    for (int m = 1; m < 8; m <<= 1){
      d0 += __shfl_xor(d0, m);
      d1 += __shfl_xor(d1, m);
      d2 += __shfl_xor(d2, m);
      d3 += __shfl_xor(d3, m);
    }
    float w0 = exp2f(d0 * ph);
    float w1 = exp2f(d1 * ph);
    float w2 = exp2f(d2 * ph);
    float w3 = exp2f(d3 * ph);
    den += (w0 + w1) + (w2 + w3);
    a0 += (w0*blo(kv0.z) + w1*blo(kv1.z)) + (w2*blo(kv2.z) + w3*blo(kv3.z));
    a1 += (w0*bhi(kv0.z) + w1*bhi(kv1.z)) + (w2*bhi(kv2.z) + w3*bhi(kv3.z));
    a2 += (w0*blo(kv0.w) + w1*blo(kv1.w)) + (w2*blo(kv2.w) + w3*blo(kv3.w));
    a3 += (w0*bhi(kv0.w) + w1*bhi(kv1.w)) + (w2*bhi(kv2.w) + w3*bhi(kv3.w));
  }
  for (; j < end; ++j){
    int s0 = srcs[j];
    uint4 kv0 = *(const uint4*)(KVl + (size_t)s0*256);
    float d0 = blo(kv0.x)*qv.x + bhi(kv0.x)*qv.y + blo(kv0.y)*qv.z + bhi(kv0.y)*qv.w;
    #pragma unroll
    for (int m = 1; m < 8; m <<= 1) d0 += __shfl_xor(d0, m);
    float w0 = exp2f(d0 * ph);
    den += w0;
    a0 += w0*blo(kv0.z);
    a1 += w0*bhi(kv0.z);
    a2 += w0*blo(kv0.w);
    a3 += w0*bhi(kv0.w);
  }
  float o[4] = {0.f, 0.f, 0.f, 0.f};
  if (end > start){
    float inv = 1.f / den;
    o[0] = gelu_exact(a0 * inv);
    o[1] = gelu_exact(a1 * inv);
    o[2] = gelu_exact(a2 * inv);
    o[3] = gelu_exact(a3 * inv);
  }
  size_t ci = (size_t)((node >> 4)*4 + h)*64 + (node & 15)*4 + ((L >> 1) & 3);
  size_t si = ci*8 + (L & 1)*4;
  uint2 uh = make_uint2((unsigned)bf16bits(o[0]) | ((unsigned)bf16bits(o[1]) << 16),
                        (unsigned)bf16bits(o[2]) | ((unsigned)bf16bits(o[3]) << 16));
  *(uint2*)(fh + si) = uh;
}

__global__ void k_decode(const int* __restrict__ pe, const int* __restrict__ ne,
                         const float* __restrict__ s1, const float* __restrict__ s2,
                         const float* __restrict__ blp, float* __restrict__ out, int P){
  int i = blockIdx.x*256 + threadIdx.x;
  if (i < P){
    out[i] = s1[pe[i]] + s2[pe[P + i]] + blp[0];
  } else if (i < 2*P){
    int j = i - P;
    out[P + j] = s1[ne[j]] + s2[ne[P + j]] + blp[0];
  }
}

extern "C" void kernel_launch(void* const* d_in, const int* in_sizes, int n_in,
                              void* d_out, int out_size, void* d_ws, size_t ws_size,
                              hipStream_t stream){
  const float* x      = (const float*)d_in[0];
  const int*   ei     = (const int*)d_in[1];
  const int*   pos_ei = (const int*)d_in[3];
  const int*   neg_ei = (const int*)d_in[4];
  const int NN = in_sizes[0] / 128;
  const int E  = in_sizes[1] / 2;
  const int P  = in_sizes[3] / 2;
  const int padM = CDIV(NN, 128) * 128;
  const int* e_src = ei;
  const int* e_dst = ei + E;

  char* wsb = (char*)d_ws;
  size_t off = 0;
  auto alloc = [&](size_t bytes)->char*{
    char* r = wsb + off;
    off = (off + bytes + 255) & ~(size_t)255;
    return r;
  };
  unsigned short* KV16 = (unsigned short*)alloc((size_t)NN*256*2);  // interleaved K/V quads
  unsigned short* Qb16 = (unsigned short*)alloc((size_t)NN*128*2);  // bf16 Q
  unsigned short* h1b  = (unsigned short*)alloc((size_t)NN*128*2);  // bf16 h1
  short* AfH    = (short*)alloc((size_t)padM*128*2);   // gelu(agg) frags from k_node
  int*   srcs   = (int*)alloc((size_t)E*4);
  int*   rowp   = (int*)alloc((size_t)(NN+1)*4);
  int*   deg    = (int*)alloc((size_t)NN*4);
  int*   cursor = (int*)alloc((size_t)NN*4);
  int*   partial= (int*)alloc(256*4);
  float* beffK1 = (float*)alloc(128*4);
  float* beffV1 = (float*)alloc(128*4);
  float* beffK2 = (float*)alloc(128*4);
  float* beffV2 = (float*)alloc(128*4);
  short* BfH1   = (short*)alloc((size_t)4*16384*2);
  short* BfH2   = (short*)alloc((size_t)4*16384*2);
  float* s1     = (float*)alloc((size_t)NN*4);
  float* s2     = (float*)alloc((size_t)NN*4);

  // ---- CSR (shared) + both layers' weight prep (one launch) ----
  const int nb = CDIV(NN, 256);     // 196 <= 256
  k_clear_int<<<CDIV(NN,256),256,0,stream>>>(deg, NN);
  k_deg<<<CDIV(E,256),256,0,stream>>>(e_dst, deg, E);
  k_scan_blk<<<nb,256,0,stream>>>(deg, rowp, partial, NN);
  k_scan_fin<<<nb,256,0,stream>>>(rowp, partial, cursor, NN, E, nb);
  k_fill<<<CDIV(E,256),256,0,stream>>>(e_src, e_dst, cursor, srcs, E);
  k_prep2<<<CDIV(2*(4*16384+256),256),256,0,stream>>>(
      (const float*)d_in[5],  (const float*)d_in[6],  (const float*)d_in[11],
      (const float*)d_in[7],  (const float*)d_in[9],  (const float*)d_in[10],
      (const float*)d_in[12], (const float*)d_in[14],
      (const float*)d_in[17], (const float*)d_in[18], (const float*)d_in[23],
      (const float*)d_in[19], (const float*)d_in[21], (const float*)d_in[22],
      (const float*)d_in[24], (const float*)d_in[26],
      BfH1, BfH2, beffK1, beffV1, beffK2, beffV2);

  const int gblk2 = padM / 32;          // 64-thread blocks, 32 rows each
  const float* Wlp = (const float*)d_in[29];

  // ---- layer 1 (fp32 x in; h1 emitted as bf16) ----
  k_kqv<false><<<gblk2,64,0,stream>>>(x, BfH1, beffK1, (const float*)d_in[8], beffV1,
                                      KV16, Qb16, NN);
  k_node<<<CDIV(NN,8),256,0,stream>>>(KV16, Qb16, srcs, rowp,
                                      (const float*)d_in[13], AfH, NN);
  k_outgemm<false,false><<<gblk2,64,0,stream>>>(AfH, BfH1, (const float*)d_in[15], x,
                                                (const float*)d_in[16], h1b,
                                                nullptr, nullptr, nullptr, NN);
  // ---- layer 2 (bf16 h1 in; decode fused; h2 never materialized) ----
  k_kqv<true><<<gblk2,64,0,stream>>>(h1b, BfH2, beffK2, (const float*)d_in[20], beffV2,
                                     KV16, Qb16, NN);
  k_node<<<CDIV(NN,8),256,0,stream>>>(KV16, Qb16, srcs, rowp,
                                      (const float*)d_in[25], AfH, NN);
  k_outgemm<true,true><<<gblk2,64,0,stream>>>(AfH, BfH2, (const float*)d_in[27], h1b,
                                              (const float*)d_in[28], nullptr,
                                              Wlp, s1, s2, NN);

  k_decode<<<CDIV(2*P,256),256,0,stream>>>(pos_ei, neg_ei, s1, s2,
                                           (const float*)d_in[30], (float*)d_out, P);
}